// Round 1
// baseline (1045.436 us; speedup 1.0000x reference)
//
#include <hip/hip_runtime.h>
#include <math.h>

#define L_SEQ 2048
#define D_EMB 1024
#define NHEADS 16
#define HD 64
#define BHEADS 32   // N*NHEADS
#define NBATCH 2
#define LN_EPS 1e-5f
#define SCALING 0.125f

// ---------------- GEMM: C = A @ B^T + bias ----------------
// A: M x K row-major, B: N x K row-major, C: M x N row-major
template<int BM, int BN, int BK>
__global__ __launch_bounds__(256) void gemm_nt(
    const float* __restrict__ A, const float* __restrict__ B,
    const float* __restrict__ bias, float* __restrict__ C,
    int M, int Nn, int K) {
  __shared__ float As[BK][BM + 4];   // [k][m], +4 keeps 16B row alignment
  __shared__ float Bs[BK][BN + 4];
  const int bm = blockIdx.y * BM;
  const int bn = blockIdx.x * BN;
  const int tid = threadIdx.x;
  const int tr = ((tid >> 4) << 2);   // 0..60
  const int tc = ((tid & 15) << 2);   // 0..60
  const int la_m = tid >> 3;          // 0..31
  const int la_k = (tid & 7) << 2;    // 0..28
  float acc[4][4] = {};
  for (int k0 = 0; k0 < K; k0 += BK) {
    #pragma unroll
    for (int mm = 0; mm < BM; mm += 32) {
      float4 v = *(const float4*)&A[(size_t)(bm + mm + la_m) * K + (k0 + la_k)];
      As[la_k + 0][mm + la_m] = v.x;
      As[la_k + 1][mm + la_m] = v.y;
      As[la_k + 2][mm + la_m] = v.z;
      As[la_k + 3][mm + la_m] = v.w;
    }
    #pragma unroll
    for (int nn = 0; nn < BN; nn += 32) {
      float4 v = *(const float4*)&B[(size_t)(bn + nn + la_m) * K + (k0 + la_k)];
      Bs[la_k + 0][nn + la_m] = v.x;
      Bs[la_k + 1][nn + la_m] = v.y;
      Bs[la_k + 2][nn + la_m] = v.z;
      Bs[la_k + 3][nn + la_m] = v.w;
    }
    __syncthreads();
    #pragma unroll
    for (int k = 0; k < BK; ++k) {
      float4 a = *(const float4*)&As[k][tr];
      float4 b = *(const float4*)&Bs[k][tc];
      acc[0][0] += a.x * b.x; acc[0][1] += a.x * b.y; acc[0][2] += a.x * b.z; acc[0][3] += a.x * b.w;
      acc[1][0] += a.y * b.x; acc[1][1] += a.y * b.y; acc[1][2] += a.y * b.z; acc[1][3] += a.y * b.w;
      acc[2][0] += a.z * b.x; acc[2][1] += a.z * b.y; acc[2][2] += a.z * b.z; acc[2][3] += a.z * b.w;
      acc[3][0] += a.w * b.x; acc[3][1] += a.w * b.y; acc[3][2] += a.w * b.z; acc[3][3] += a.w * b.w;
    }
    __syncthreads();
  }
  float4 bb = *(const float4*)&bias[bn + tc];
  #pragma unroll
  for (int i = 0; i < 4; ++i) {
    float4 o;
    o.x = acc[i][0] + bb.x; o.y = acc[i][1] + bb.y;
    o.z = acc[i][2] + bb.z; o.w = acc[i][3] + bb.w;
    *(float4*)&C[(size_t)(bm + tr + i) * Nn + (bn + tc)] = o;
  }
}

// ------------- q_temp = LN(gelu(q_head @ Wc^T + bc)); q_rel_sum = sum_l q_temp -------------
// grid (BHEADS, 16 chunks), block 256 (4 waves, each wave owns one l at a time; o = lane)
__global__ __launch_bounds__(256) void qtemp_qrel_kernel(
    const float* __restrict__ qkv, const float* __restrict__ Wc,
    const float* __restrict__ bc, const float* __restrict__ gamma,
    const float* __restrict__ beta, float* __restrict__ q_rel_sum) {
  __shared__ float Wc_s[64][65];
  __shared__ float q_s[4][64];
  __shared__ float red[4][64];
  const int b = blockIdx.x;
  const int n = b >> 4, h = b & 15;
  const int tid = threadIdx.x;
  const int wave = tid >> 6;
  const int o = tid & 63;
  for (int i = tid; i < 64 * 64; i += 256) Wc_s[i >> 6][i & 63] = Wc[i];
  __syncthreads();
  const float bco = bc[o];
  const float go = gamma[o];
  const float bo = beta[o];
  float accum = 0.f;
  const int l0 = blockIdx.y * 128 + wave * 32;
  for (int li = 0; li < 32; ++li) {
    const int l = l0 + li;
    q_s[wave][o] = qkv[((size_t)(n * L_SEQ + l)) * (3 * D_EMB) + h * 64 + o];
    __syncthreads();
    float dot = bco;
    #pragma unroll
    for (int c = 0; c < 64; ++c) dot += q_s[wave][c] * Wc_s[o][c];
    __syncthreads();
    // exact gelu
    float g = 0.5f * dot * (1.f + erff(dot * 0.70710678118654752f));
    // wave-wide LN over 64 lanes
    float s1 = g, s2 = g * g;
    #pragma unroll
    for (int off = 32; off > 0; off >>= 1) {
      s1 += __shfl_xor(s1, off);
      s2 += __shfl_xor(s2, off);
    }
    float mu = s1 * (1.f / 64.f);
    float var = s2 * (1.f / 64.f) - mu * mu;
    float y = (g - mu) * rsqrtf(var + LN_EPS) * go + bo;
    accum += y;
  }
  red[wave][o] = accum;
  __syncthreads();
  if (wave == 0) {
    float tot = red[0][o] + red[1][o] + red[2][o] + red[3][o];
    atomicAdd(&q_rel_sum[b * 64 + o], tot);
  }
}

// ------------- w_row[b,t] = (SCALING/L) * dot(q_rel_sum[b,:], k_head[b,t,:]) -------------
__global__ __launch_bounds__(256) void wrow_kernel(
    const float* __restrict__ qkv, const float* __restrict__ q_rel_sum,
    float* __restrict__ w_row) {
  const int b = blockIdx.x;
  const int n = b >> 4, h = b & 15;
  __shared__ float q_s[64];
  if (threadIdx.x < 64)
    q_s[threadIdx.x] = q_rel_sum[b * 64 + threadIdx.x] * (SCALING / (float)L_SEQ);
  __syncthreads();
  for (int t = threadIdx.x; t < L_SEQ; t += 256) {
    const float* kp = &qkv[((size_t)(n * L_SEQ + t)) * (3 * D_EMB) + D_EMB + h * 64];
    float acc = 0.f;
    #pragma unroll
    for (int c = 0; c < 64; c += 4) {
      float4 kv = *(const float4*)&kp[c];
      acc += q_s[c] * kv.x + q_s[c + 1] * kv.y + q_s[c + 2] * kv.z + q_s[c + 3] * kv.w;
    }
    w_row[b * L_SEQ + t] = acc;
  }
}

// ------------- e[t]=exp(w[t]-max); denom[i]=prefix_sum(e); inv[i]=1/denom[i] -------------
__global__ __launch_bounds__(256) void scan_kernel(
    const float* __restrict__ w_row, float* __restrict__ e_out,
    float* __restrict__ inv_out) {
  const int b = blockIdx.x;
  const int tid = threadIdx.x;
  __shared__ float sh[L_SEQ];
  __shared__ float ts[256];
  const float* wb = w_row + b * L_SEQ;
  float m = -3.4e38f;
  for (int i = tid; i < L_SEQ; i += 256) {
    float v = wb[i];
    sh[i] = v;
    m = fmaxf(m, v);
  }
  ts[tid] = m;
  __syncthreads();
  for (int off = 128; off > 0; off >>= 1) {
    if (tid < off) ts[tid] = fmaxf(ts[tid], ts[tid + off]);
    __syncthreads();
  }
  const float mx = ts[0];
  __syncthreads();
  const int t0 = tid * 8;
  float loc[8];
  float run = 0.f;
  #pragma unroll
  for (int k = 0; k < 8; ++k) {
    float ev = expf(sh[t0 + k] - mx);
    e_out[b * L_SEQ + t0 + k] = ev;
    run += ev;
    loc[k] = run;
  }
  ts[tid] = run;
  __syncthreads();
  for (int off = 1; off < 256; off <<= 1) {
    float v = ts[tid];
    float add = (tid >= off) ? ts[tid - off] : 0.f;
    __syncthreads();
    ts[tid] = v + add;
    __syncthreads();
  }
  float prefix = (tid > 0) ? ts[tid - 1] : 0.f;
  #pragma unroll
  for (int k = 0; k < 8; ++k) {
    inv_out[b * L_SEQ + t0 + k] = 1.f / (prefix + loc[k]);
  }
}

// ------------- attn_out[b,i,:] = inv[i] * sum_{t<=i} e[t] * v[b,i-t,:] (causal conv) -------------
// grid (32 i-tiles, BHEADS), block 256: thread = (il=tid/16 in [0,16), d4=(tid&15)*4)
// each thread owns rows i0 + il + 16*r, r in [0,4)
__global__ __launch_bounds__(256) void conv_kernel(
    const float* __restrict__ qkv, const float* __restrict__ e_arr,
    const float* __restrict__ inv_arr, float* __restrict__ attn_out) {
  const int b = blockIdx.y;
  const int n = b >> 4, h = b & 15;
  const int i0 = blockIdx.x * 64;
  const int tid = threadIdx.x;
  const int il = tid >> 4;
  const int d4 = (tid & 15) << 2;
  __shared__ float v_s[64][64];
  __shared__ float e_s[128];
  float4 acc[4];
  #pragma unroll
  for (int r = 0; r < 4; ++r) acc[r] = make_float4(0.f, 0.f, 0.f, 0.f);
  const float* e_b = e_arr + b * L_SEQ;
  const float* vbase = qkv + 2 * (size_t)D_EMB + h * 64 + (size_t)n * L_SEQ * (3 * D_EMB);
  for (int jt = 0; jt <= blockIdx.x; ++jt) {
    const int j0 = jt * 64;
    for (int idx = tid; idx < 64 * 16; idx += 256) {
      const int jj = idx >> 4;
      const int c4 = (idx & 15) << 2;
      float4 val = *(const float4*)&vbase[(size_t)(j0 + jj) * (3 * D_EMB) + c4];
      *(float4*)&v_s[jj][c4] = val;
    }
    if (tid < 128) {
      int lag = tid + i0 - j0 - 63;
      e_s[tid] = (lag >= 0 && lag < L_SEQ) ? e_b[lag] : 0.f;
    }
    __syncthreads();
    #pragma unroll 4
    for (int jj = 0; jj < 64; ++jj) {
      float4 v4 = *(const float4*)&v_s[jj][d4];
      const int ebase = il - jj + 63;
      float e0 = e_s[ebase];
      float e1 = e_s[ebase + 16];
      float e2 = e_s[ebase + 32];
      float e3 = e_s[ebase + 48];
      acc[0].x += e0 * v4.x; acc[0].y += e0 * v4.y; acc[0].z += e0 * v4.z; acc[0].w += e0 * v4.w;
      acc[1].x += e1 * v4.x; acc[1].y += e1 * v4.y; acc[1].z += e1 * v4.z; acc[1].w += e1 * v4.w;
      acc[2].x += e2 * v4.x; acc[2].y += e2 * v4.y; acc[2].z += e2 * v4.z; acc[2].w += e2 * v4.w;
      acc[3].x += e3 * v4.x; acc[3].y += e3 * v4.y; acc[3].z += e3 * v4.z; acc[3].w += e3 * v4.w;
    }
    __syncthreads();
  }
  #pragma unroll
  for (int r = 0; r < 4; ++r) {
    const int i = i0 + il + 16 * r;
    const float iv = inv_arr[b * L_SEQ + i];
    float4 o = acc[r];
    o.x *= iv; o.y *= iv; o.z *= iv; o.w *= iv;
    *(float4*)&attn_out[((size_t)(n * L_SEQ + i)) * D_EMB + h * 64 + d4] = o;
  }
}

// ------------- wm[b,j] = (1/L) * sum_{i>=j} e[i-j]*inv[i] -------------
__global__ __launch_bounds__(256) void wmean_kernel(
    const float* __restrict__ e_arr, const float* __restrict__ inv_arr,
    float* __restrict__ out_wm) {
  const int b = blockIdx.x;
  const int j = blockIdx.y * 256 + threadIdx.x;
  const float* e_b = e_arr + b * L_SEQ;
  const float* inv_b = inv_arr + b * L_SEQ;
  float acc = 0.f;
  for (int i = j; i < L_SEQ; ++i) acc += e_b[i - j] * inv_b[i];
  out_wm[b * L_SEQ + j] = acc * (1.f / (float)L_SEQ);
}

extern "C" void kernel_launch(void* const* d_in, const int* in_sizes, int n_in,
                              void* d_out, int out_size, void* d_ws, size_t ws_size,
                              hipStream_t stream) {
  const float* x       = (const float*)d_in[0];
  const float* W_in    = (const float*)d_in[1];
  const float* b_in    = (const float*)d_in[2];
  const float* Wc      = (const float*)d_in[3];
  const float* bc      = (const float*)d_in[4];
  const float* gamma   = (const float*)d_in[5];
  const float* beta    = (const float*)d_in[6];
  const float* W_out   = (const float*)d_in[7];
  const float* b_out   = (const float*)d_in[8];
  float* out = (float*)d_out;

  const int M = NBATCH * L_SEQ;      // 4096
  // workspace layout (floats)
  float* ws = (float*)d_ws;
  float* qkv   = ws;                                   // 12,582,912
  float* attn  = qkv + (size_t)M * 3 * D_EMB;          // 4,194,304
  float* q_rel = attn + (size_t)M * D_EMB;             // 2048
  float* w_row = q_rel + BHEADS * HD;                  // 65,536
  float* e_arr = w_row + BHEADS * L_SEQ;               // 65,536
  float* inv_a = e_arr + BHEADS * L_SEQ;               // 65,536

  hipMemsetAsync(q_rel, 0, BHEADS * HD * sizeof(float), stream);

  // 1) qkv = x @ W_in^T + b_in
  gemm_nt<64, 64, 32><<<dim3(3 * D_EMB / 64, M / 64), 256, 0, stream>>>(
      x, W_in, b_in, qkv, M, 3 * D_EMB, D_EMB);
  // 2) q_temp -> q_rel sums
  qtemp_qrel_kernel<<<dim3(BHEADS, 16), 256, 0, stream>>>(
      qkv, Wc, bc, gamma, beta, q_rel);
  // 3) w_row
  wrow_kernel<<<dim3(BHEADS), 256, 0, stream>>>(qkv, q_rel, w_row);
  // 4) softmax scan
  scan_kernel<<<dim3(BHEADS), 256, 0, stream>>>(w_row, e_arr, inv_a);
  // 5) causal conv -> attn_out (already in (N,L,D) layout)
  conv_kernel<<<dim3(L_SEQ / 64, BHEADS), 256, 0, stream>>>(qkv, e_arr, inv_a, attn);
  // 6) weights.mean(axis=1) -> second output
  wmean_kernel<<<dim3(BHEADS, L_SEQ / 256), 256, 0, stream>>>(
      e_arr, inv_a, out + (size_t)M * D_EMB);
  // 7) output = attn @ W_out^T + b_out
  gemm_nt<64, 64, 32><<<dim3(D_EMB / 64, M / 64), 256, 0, stream>>>(
      attn, W_out, b_out, out, M, D_EMB, D_EMB);
}

// Round 2
// 637.727 us; speedup vs baseline: 1.6393x; 1.6393x over previous
//
#include <hip/hip_runtime.h>
#include <math.h>

#define L_SEQ 2048
#define D_EMB 1024
#define NHEADS 16
#define HD 64
#define BHEADS 32   // N*NHEADS
#define NBATCH 2
#define LN_EPS 1e-5f
#define SCALING 0.125f

typedef __attribute__((ext_vector_type(8))) __bf16 bf16x8;
typedef __attribute__((ext_vector_type(4))) float f32x4;
typedef const __attribute__((address_space(1))) unsigned int* gptr_as1;
typedef __attribute__((address_space(3))) unsigned int* lptr_as3;

__device__ __forceinline__ void load16_to_lds(const void* g, void* l) {
  __builtin_amdgcn_global_load_lds((gptr_as1)g, (lptr_as3)l, 16, 0, 0);
}

__device__ __forceinline__ unsigned short f2bf(float f) {
  unsigned int u = __float_as_uint(f);
  u += 0x7fff + ((u >> 16) & 1);   // round-to-nearest-even
  return (unsigned short)(u >> 16);
}

// ---------------- fp32 -> bf16 convert (RNE), 4 elems/thread ----------------
__global__ __launch_bounds__(256) void cvt_bf16_kernel(
    const float* __restrict__ in, unsigned short* __restrict__ out, int n) {
  int i = (blockIdx.x * 256 + threadIdx.x) * 4;
  if (i < n) {
    float4 v = *(const float4*)&in[i];
    ushort4 o;
    o.x = f2bf(v.x); o.y = f2bf(v.y); o.z = f2bf(v.z); o.w = f2bf(v.w);
    *(ushort4*)&out[i] = o;
  }
}

// ---------------- bf16 MFMA GEMM: C_f32 = A @ B^T + bias ----------------
// A: M x K row-major bf16, B: N x K row-major bf16, C: M x N row-major f32
// 128x128 tile, BK=32, 4 waves (2x2 of 64x64), 16x16x32 MFMA.
// LDS is fragment-major: chunk c (16B = 8 bf16) holds rows g*16+m, cols q*8..q*8+7
// with c = ((g*4+q)*16 + m); staging via global_load_lds is lane-linear.
__global__ __launch_bounds__(256) void gemm_bt_bf16(
    const unsigned short* __restrict__ A, const unsigned short* __restrict__ B,
    const float* __restrict__ bias, float* __restrict__ C,
    int M, int Nn, int K) {
  __shared__ unsigned short As[4096];   // 128x32 bf16, fragment-major
  __shared__ unsigned short Bs[4096];
  const int bm = blockIdx.y * 128;
  const int bn = blockIdx.x * 128;
  const int tid = threadIdx.x;
  const int lane = tid & 63;
  const int wave = tid >> 6;
  const int wr = (wave >> 1) * 64;   // wave row offset in tile
  const int wc = (wave & 1) * 64;    // wave col offset in tile

  // staging chunks owned by this thread
  const int c0 = tid, c1 = tid + 256;
  const unsigned short* ga0 = A + (size_t)(bm + (c0 >> 6) * 16 + (c0 & 15)) * K + ((c0 >> 4) & 3) * 8;
  const unsigned short* ga1 = A + (size_t)(bm + (c1 >> 6) * 16 + (c1 & 15)) * K + ((c1 >> 4) & 3) * 8;
  const unsigned short* gb0 = B + (size_t)(bn + (c0 >> 6) * 16 + (c0 & 15)) * K + ((c0 >> 4) & 3) * 8;
  const unsigned short* gb1 = B + (size_t)(bn + (c1 >> 6) * 16 + (c1 & 15)) * K + ((c1 >> 4) & 3) * 8;
  unsigned short* la0 = &As[c0 * 8];
  unsigned short* la1 = &As[c1 * 8];
  unsigned short* lb0 = &Bs[c0 * 8];
  unsigned short* lb1 = &Bs[c1 * 8];

  f32x4 acc[4][4] = {};
  for (int k0 = 0; k0 < K; k0 += 32) {
    load16_to_lds(ga0 + k0, la0);
    load16_to_lds(ga1 + k0, la1);
    load16_to_lds(gb0 + k0, lb0);
    load16_to_lds(gb1 + k0, lb1);
    __syncthreads();
    bf16x8 af[4], bf[4];
    #pragma unroll
    for (int i = 0; i < 4; ++i)
      af[i] = *(const bf16x8*)&As[((wr >> 4) + i) * 512 + lane * 8];
    #pragma unroll
    for (int j = 0; j < 4; ++j)
      bf[j] = *(const bf16x8*)&Bs[((wc >> 4) + j) * 512 + lane * 8];
    #pragma unroll
    for (int i = 0; i < 4; ++i)
      #pragma unroll
      for (int j = 0; j < 4; ++j)
        acc[i][j] = __builtin_amdgcn_mfma_f32_16x16x32_bf16(af[i], bf[j], acc[i][j], 0, 0, 0);
    __syncthreads();
  }
  // epilogue: C/D layout col=lane&15, row=(lane>>4)*4+reg
  const int lc = lane & 15;
  const int lr4 = (lane >> 4) * 4;
  float bv[4];
  #pragma unroll
  for (int j = 0; j < 4; ++j) bv[j] = bias[bn + wc + j * 16 + lc];
  #pragma unroll
  for (int i = 0; i < 4; ++i) {
    #pragma unroll
    for (int r = 0; r < 4; ++r) {
      const int row = bm + wr + i * 16 + lr4 + r;
      float* cp = &C[(size_t)row * Nn + bn + wc + lc];
      #pragma unroll
      for (int j = 0; j < 4; ++j) cp[j * 16] = acc[i][j][r] + bv[j];
    }
  }
}

// ------------- q_temp = LN(gelu(q_head @ Wc^T + bc)); q_rel_sum = sum_l q_temp -------------
__global__ __launch_bounds__(256) void qtemp_qrel_kernel(
    const float* __restrict__ qkv, const float* __restrict__ Wc,
    const float* __restrict__ bc, const float* __restrict__ gamma,
    const float* __restrict__ beta, float* __restrict__ q_rel_sum) {
  __shared__ float Wc_s[64][65];
  __shared__ float q_s[4][64];
  __shared__ float red[4][64];
  const int b = blockIdx.x;
  const int n = b >> 4, h = b & 15;
  const int tid = threadIdx.x;
  const int wave = tid >> 6;
  const int o = tid & 63;
  for (int i = tid; i < 64 * 64; i += 256) Wc_s[i >> 6][i & 63] = Wc[i];
  __syncthreads();
  const float bco = bc[o];
  const float go = gamma[o];
  const float bo = beta[o];
  float accum = 0.f;
  const int l0 = blockIdx.y * 128 + wave * 32;
  for (int li = 0; li < 32; ++li) {
    const int l = l0 + li;
    q_s[wave][o] = qkv[((size_t)(n * L_SEQ + l)) * (3 * D_EMB) + h * 64 + o];
    __syncthreads();
    float dot = bco;
    #pragma unroll
    for (int c = 0; c < 64; ++c) dot += q_s[wave][c] * Wc_s[o][c];
    __syncthreads();
    float g = 0.5f * dot * (1.f + erff(dot * 0.70710678118654752f));
    float s1 = g, s2 = g * g;
    #pragma unroll
    for (int off = 32; off > 0; off >>= 1) {
      s1 += __shfl_xor(s1, off);
      s2 += __shfl_xor(s2, off);
    }
    float mu = s1 * (1.f / 64.f);
    float var = s2 * (1.f / 64.f) - mu * mu;
    float y = (g - mu) * rsqrtf(var + LN_EPS) * go + bo;
    accum += y;
  }
  red[wave][o] = accum;
  __syncthreads();
  if (wave == 0) {
    float tot = red[0][o] + red[1][o] + red[2][o] + red[3][o];
    atomicAdd(&q_rel_sum[b * 64 + o], tot);
  }
}

// ------------- w_row[b,t] = (SCALING/L) * dot(q_rel_sum[b,:], k_head[b,t,:]) -------------
__global__ __launch_bounds__(256) void wrow_kernel(
    const float* __restrict__ qkv, const float* __restrict__ q_rel_sum,
    float* __restrict__ w_row) {
  const int b = blockIdx.x;
  const int n = b >> 4, h = b & 15;
  __shared__ float q_s[64];
  if (threadIdx.x < 64)
    q_s[threadIdx.x] = q_rel_sum[b * 64 + threadIdx.x] * (SCALING / (float)L_SEQ);
  __syncthreads();
  for (int t = threadIdx.x; t < L_SEQ; t += 256) {
    const float* kp = &qkv[((size_t)(n * L_SEQ + t)) * (3 * D_EMB) + D_EMB + h * 64];
    float acc = 0.f;
    #pragma unroll
    for (int c = 0; c < 64; c += 4) {
      float4 kv = *(const float4*)&kp[c];
      acc += q_s[c] * kv.x + q_s[c + 1] * kv.y + q_s[c + 2] * kv.z + q_s[c + 3] * kv.w;
    }
    w_row[b * L_SEQ + t] = acc;
  }
}

// ------------- e[t]=exp(w[t]-max); inv[i]=1/prefix_sum(e) -------------
__global__ __launch_bounds__(256) void scan_kernel(
    const float* __restrict__ w_row, float* __restrict__ e_out,
    float* __restrict__ inv_out) {
  const int b = blockIdx.x;
  const int tid = threadIdx.x;
  __shared__ float sh[L_SEQ];
  __shared__ float ts[256];
  const float* wb = w_row + b * L_SEQ;
  float m = -3.4e38f;
  for (int i = tid; i < L_SEQ; i += 256) {
    float v = wb[i];
    sh[i] = v;
    m = fmaxf(m, v);
  }
  ts[tid] = m;
  __syncthreads();
  for (int off = 128; off > 0; off >>= 1) {
    if (tid < off) ts[tid] = fmaxf(ts[tid], ts[tid + off]);
    __syncthreads();
  }
  const float mx = ts[0];
  __syncthreads();
  const int t0 = tid * 8;
  float loc[8];
  float run = 0.f;
  #pragma unroll
  for (int k = 0; k < 8; ++k) {
    float ev = expf(sh[t0 + k] - mx);
    e_out[b * L_SEQ + t0 + k] = ev;
    run += ev;
    loc[k] = run;
  }
  ts[tid] = run;
  __syncthreads();
  for (int off = 1; off < 256; off <<= 1) {
    float v = ts[tid];
    float add = (tid >= off) ? ts[tid - off] : 0.f;
    __syncthreads();
    ts[tid] = v + add;
    __syncthreads();
  }
  float prefix = (tid > 0) ? ts[tid - 1] : 0.f;
  #pragma unroll
  for (int k = 0; k < 8; ++k) {
    inv_out[b * L_SEQ + t0 + k] = 1.f / (prefix + loc[k]);
  }
}

// ------------- attn_out[b,i,:] = inv[i] * sum_{t<=i} e[t]*v[b,i-t,:]; writes bf16 -------------
__global__ __launch_bounds__(256) void conv_kernel(
    const float* __restrict__ qkv, const float* __restrict__ e_arr,
    const float* __restrict__ inv_arr, unsigned short* __restrict__ attn_out) {
  const int b = blockIdx.y;
  const int n = b >> 4, h = b & 15;
  const int i0 = blockIdx.x * 64;
  const int tid = threadIdx.x;
  const int il = tid >> 4;
  const int d4 = (tid & 15) << 2;
  __shared__ float v_s[64][64];
  __shared__ float e_s[128];
  float4 acc[4];
  #pragma unroll
  for (int r = 0; r < 4; ++r) acc[r] = make_float4(0.f, 0.f, 0.f, 0.f);
  const float* e_b = e_arr + b * L_SEQ;
  const float* vbase = qkv + 2 * (size_t)D_EMB + h * 64 + (size_t)n * L_SEQ * (3 * D_EMB);
  for (int jt = 0; jt <= blockIdx.x; ++jt) {
    const int j0 = jt * 64;
    for (int idx = tid; idx < 64 * 16; idx += 256) {
      const int jj = idx >> 4;
      const int c4 = (idx & 15) << 2;
      float4 val = *(const float4*)&vbase[(size_t)(j0 + jj) * (3 * D_EMB) + c4];
      *(float4*)&v_s[jj][c4] = val;
    }
    if (tid < 128) {
      int lag = tid + i0 - j0 - 63;
      e_s[tid] = (lag >= 0 && lag < L_SEQ) ? e_b[lag] : 0.f;
    }
    __syncthreads();
    #pragma unroll 4
    for (int jj = 0; jj < 64; ++jj) {
      float4 v4 = *(const float4*)&v_s[jj][d4];
      const int ebase = il - jj + 63;
      float e0 = e_s[ebase];
      float e1 = e_s[ebase + 16];
      float e2 = e_s[ebase + 32];
      float e3 = e_s[ebase + 48];
      acc[0].x += e0 * v4.x; acc[0].y += e0 * v4.y; acc[0].z += e0 * v4.z; acc[0].w += e0 * v4.w;
      acc[1].x += e1 * v4.x; acc[1].y += e1 * v4.y; acc[1].z += e1 * v4.z; acc[1].w += e1 * v4.w;
      acc[2].x += e2 * v4.x; acc[2].y += e2 * v4.y; acc[2].z += e2 * v4.z; acc[2].w += e2 * v4.w;
      acc[3].x += e3 * v4.x; acc[3].y += e3 * v4.y; acc[3].z += e3 * v4.z; acc[3].w += e3 * v4.w;
    }
    __syncthreads();
  }
  #pragma unroll
  for (int r = 0; r < 4; ++r) {
    const int i = i0 + il + 16 * r;
    const float iv = inv_arr[b * L_SEQ + i];
    ushort4 o;
    o.x = f2bf(acc[r].x * iv);
    o.y = f2bf(acc[r].y * iv);
    o.z = f2bf(acc[r].z * iv);
    o.w = f2bf(acc[r].w * iv);
    *(ushort4*)&attn_out[((size_t)(n * L_SEQ + i)) * D_EMB + h * 64 + d4] = o;
  }
}

// ------------- wm[b,j] = (1/L) * sum_{i>=j} e[i-j]*inv[i] -------------
__global__ __launch_bounds__(256) void wmean_kernel(
    const float* __restrict__ e_arr, const float* __restrict__ inv_arr,
    float* __restrict__ out_wm) {
  const int b = blockIdx.x;
  const int j = blockIdx.y * 256 + threadIdx.x;
  const float* e_b = e_arr + b * L_SEQ;
  const float* inv_b = inv_arr + b * L_SEQ;
  float acc = 0.f;
  for (int i = j; i < L_SEQ; ++i) acc += e_b[i - j] * inv_b[i];
  out_wm[b * L_SEQ + j] = acc * (1.f / (float)L_SEQ);
}

extern "C" void kernel_launch(void* const* d_in, const int* in_sizes, int n_in,
                              void* d_out, int out_size, void* d_ws, size_t ws_size,
                              hipStream_t stream) {
  const float* x       = (const float*)d_in[0];
  const float* W_in    = (const float*)d_in[1];
  const float* b_in    = (const float*)d_in[2];
  const float* Wc      = (const float*)d_in[3];
  const float* bc      = (const float*)d_in[4];
  const float* gamma   = (const float*)d_in[5];
  const float* beta    = (const float*)d_in[6];
  const float* W_out   = (const float*)d_in[7];
  const float* b_out   = (const float*)d_in[8];
  float* out = (float*)d_out;

  const int M = NBATCH * L_SEQ;      // 4096
  // workspace layout (bytes); peak ~65.8 MB (< round-1's proven 67.4 MB)
  char* ws = (char*)d_ws;
  float* qkv            = (float*)ws;                               // 50,331,648 B
  unsigned short* xa_bf = (unsigned short*)(ws + 50331648);         //  8,388,608 B (x_bf, later attn_bf)
  unsigned short* Win_bf= (unsigned short*)(ws + 50331648 + 8388608); // 6,291,456 B
  float* q_rel = (float*)(ws + 50331648 + 8388608 + 6291456);       //      8,192 B
  float* w_row = q_rel + BHEADS * HD;                               //    262,144 B
  float* e_arr = w_row + BHEADS * L_SEQ;
  float* inv_a = e_arr + BHEADS * L_SEQ;
  unsigned short* Wout_bf = (unsigned short*)ws;                    // aliases dead qkv (after conv)

  hipMemsetAsync(q_rel, 0, BHEADS * HD * sizeof(float), stream);

  // 0) convert x and W_in to bf16
  cvt_bf16_kernel<<<dim3(M * D_EMB / 1024), 256, 0, stream>>>(x, xa_bf, M * D_EMB);
  cvt_bf16_kernel<<<dim3(3 * D_EMB * D_EMB / 1024), 256, 0, stream>>>(W_in, Win_bf, 3 * D_EMB * D_EMB);
  // 1) qkv = x @ W_in^T + b_in   (bf16 MFMA, fp32 out)
  gemm_bt_bf16<<<dim3(3 * D_EMB / 128, M / 128), 256, 0, stream>>>(
      xa_bf, Win_bf, b_in, qkv, M, 3 * D_EMB, D_EMB);
  // 2) q_temp -> q_rel sums
  qtemp_qrel_kernel<<<dim3(BHEADS, 16), 256, 0, stream>>>(
      qkv, Wc, bc, gamma, beta, q_rel);
  // 3) w_row
  wrow_kernel<<<dim3(BHEADS), 256, 0, stream>>>(qkv, q_rel, w_row);
  // 4) softmax scan
  scan_kernel<<<dim3(BHEADS), 256, 0, stream>>>(w_row, e_arr, inv_a);
  // 5) causal conv -> attn (bf16, reuses x_bf region; qkv v-part consumed here)
  conv_kernel<<<dim3(L_SEQ / 64, BHEADS), 256, 0, stream>>>(qkv, e_arr, inv_a, xa_bf);
  // 6) convert W_out (into dead qkv region)
  cvt_bf16_kernel<<<dim3(D_EMB * D_EMB / 1024), 256, 0, stream>>>(W_out, Wout_bf, D_EMB * D_EMB);
  // 7) weights.mean(axis=1) -> second output
  wmean_kernel<<<dim3(BHEADS, L_SEQ / 256), 256, 0, stream>>>(
      e_arr, inv_a, out + (size_t)M * D_EMB);
  // 8) output = attn @ W_out^T + b_out  (bf16 MFMA, fp32 out)
  gemm_bt_bf16<<<dim3(D_EMB / 128, M / 128), 256, 0, stream>>>(
      xa_bf, Wout_bf, b_out, out, M, D_EMB, D_EMB);
}

// Round 3
// 394.667 us; speedup vs baseline: 2.6489x; 1.6159x over previous
//
#include <hip/hip_runtime.h>
#include <math.h>

#define L_SEQ 2048
#define D_EMB 1024
#define NHEADS 16
#define HD 64
#define BHEADS 32   // N*NHEADS
#define NBATCH 2
#define LN_EPS 1e-5f
#define SCALING 0.125f

typedef __attribute__((ext_vector_type(8))) __bf16 bf16x8;
typedef __attribute__((ext_vector_type(4))) float f32x4;
typedef const __attribute__((address_space(1))) unsigned int* gptr_as1;
typedef __attribute__((address_space(3))) unsigned int* lptr_as3;

__device__ __forceinline__ void load16_to_lds(const void* g, void* l) {
  __builtin_amdgcn_global_load_lds((gptr_as1)g, (lptr_as3)l, 16, 0, 0);
}

__device__ __forceinline__ unsigned short f2bf(float f) {
  unsigned int u = __float_as_uint(f);
  u += 0x7fff + ((u >> 16) & 1);   // round-to-nearest-even
  return (unsigned short)(u >> 16);
}

// ---------------- fp32 -> bf16 convert (RNE), 4 elems/thread ----------------
__global__ __launch_bounds__(256) void cvt_bf16_kernel(
    const float* __restrict__ in, unsigned short* __restrict__ out, int n) {
  int i = (blockIdx.x * 256 + threadIdx.x) * 4;
  if (i < n) {
    float4 v = *(const float4*)&in[i];
    ushort4 o;
    o.x = f2bf(v.x); o.y = f2bf(v.y); o.z = f2bf(v.z); o.w = f2bf(v.w);
    *(ushort4*)&out[i] = o;
  }
}

// ---------------- bf16 MFMA GEMM: C_f32 = A @ B^T + bias ----------------
__global__ __launch_bounds__(256) void gemm_bt_bf16(
    const unsigned short* __restrict__ A, const unsigned short* __restrict__ B,
    const float* __restrict__ bias, float* __restrict__ C,
    int M, int Nn, int K) {
  __shared__ unsigned short As[4096];   // 128x32 bf16, fragment-major
  __shared__ unsigned short Bs[4096];
  const int bm = blockIdx.y * 128;
  const int bn = blockIdx.x * 128;
  const int tid = threadIdx.x;
  const int lane = tid & 63;
  const int wave = tid >> 6;
  const int wr = (wave >> 1) * 64;
  const int wc = (wave & 1) * 64;

  const int c0 = tid, c1 = tid + 256;
  const unsigned short* ga0 = A + (size_t)(bm + (c0 >> 6) * 16 + (c0 & 15)) * K + ((c0 >> 4) & 3) * 8;
  const unsigned short* ga1 = A + (size_t)(bm + (c1 >> 6) * 16 + (c1 & 15)) * K + ((c1 >> 4) & 3) * 8;
  const unsigned short* gb0 = B + (size_t)(bn + (c0 >> 6) * 16 + (c0 & 15)) * K + ((c0 >> 4) & 3) * 8;
  const unsigned short* gb1 = B + (size_t)(bn + (c1 >> 6) * 16 + (c1 & 15)) * K + ((c1 >> 4) & 3) * 8;
  unsigned short* la0 = &As[c0 * 8];
  unsigned short* la1 = &As[c1 * 8];
  unsigned short* lb0 = &Bs[c0 * 8];
  unsigned short* lb1 = &Bs[c1 * 8];

  f32x4 acc[4][4] = {};
  for (int k0 = 0; k0 < K; k0 += 32) {
    load16_to_lds(ga0 + k0, la0);
    load16_to_lds(ga1 + k0, la1);
    load16_to_lds(gb0 + k0, lb0);
    load16_to_lds(gb1 + k0, lb1);
    __syncthreads();
    bf16x8 af[4], bf[4];
    #pragma unroll
    for (int i = 0; i < 4; ++i)
      af[i] = *(const bf16x8*)&As[((wr >> 4) + i) * 512 + lane * 8];
    #pragma unroll
    for (int j = 0; j < 4; ++j)
      bf[j] = *(const bf16x8*)&Bs[((wc >> 4) + j) * 512 + lane * 8];
    #pragma unroll
    for (int i = 0; i < 4; ++i)
      #pragma unroll
      for (int j = 0; j < 4; ++j)
        acc[i][j] = __builtin_amdgcn_mfma_f32_16x16x32_bf16(af[i], bf[j], acc[i][j], 0, 0, 0);
    __syncthreads();
  }
  const int lc = lane & 15;
  const int lr4 = (lane >> 4) * 4;
  float bv[4];
  #pragma unroll
  for (int j = 0; j < 4; ++j) bv[j] = bias[bn + wc + j * 16 + lc];
  #pragma unroll
  for (int i = 0; i < 4; ++i) {
    #pragma unroll
    for (int r = 0; r < 4; ++r) {
      const int row = bm + wr + i * 16 + lr4 + r;
      float* cp = &C[(size_t)row * Nn + bn + wc + lc];
      #pragma unroll
      for (int j = 0; j < 4; ++j) cp[j * 16] = acc[i][j][r] + bv[j];
    }
  }
}

// ------------- q_temp = LN(gelu(q_head @ Wc^T + bc)); q_rel_sum = sum_l q_temp -------------
// per-wave LDS buffers: no block barriers in the main loop
__global__ __launch_bounds__(256) void qtemp_qrel_kernel(
    const float* __restrict__ qkv, const float* __restrict__ Wc,
    const float* __restrict__ bc, const float* __restrict__ gamma,
    const float* __restrict__ beta, float* __restrict__ q_rel_sum) {
  __shared__ float Wc_s[64][65];
  __shared__ float q_s[4][64];
  __shared__ float red[4][64];
  const int b = blockIdx.x;
  const int n = b >> 4, h = b & 15;
  const int tid = threadIdx.x;
  const int wave = tid >> 6;
  const int o = tid & 63;
  for (int i = tid; i < 64 * 64; i += 256) Wc_s[i >> 6][i & 63] = Wc[i];
  __syncthreads();
  const float bco = bc[o];
  const float go = gamma[o];
  const float bo = beta[o];
  float accum = 0.f;
  const int l0 = blockIdx.y * 128 + wave * 32;
  for (int li = 0; li < 32; ++li) {
    const int l = l0 + li;
    q_s[wave][o] = qkv[((size_t)(n * L_SEQ + l)) * (3 * D_EMB) + h * 64 + o];
    // per-wave LDS, lockstep wave: no barrier needed
    float dot = bco;
    #pragma unroll
    for (int c = 0; c < 64; ++c) dot += q_s[wave][c] * Wc_s[o][c];
    float g = 0.5f * dot * (1.f + erff(dot * 0.70710678118654752f));
    float s1 = g, s2 = g * g;
    #pragma unroll
    for (int off = 32; off > 0; off >>= 1) {
      s1 += __shfl_xor(s1, off);
      s2 += __shfl_xor(s2, off);
    }
    float mu = s1 * (1.f / 64.f);
    float var = s2 * (1.f / 64.f) - mu * mu;
    float y = (g - mu) * rsqrtf(var + LN_EPS) * go + bo;
    accum += y;
  }
  red[wave][o] = accum;
  __syncthreads();
  if (wave == 0) {
    float tot = red[0][o] + red[1][o] + red[2][o] + red[3][o];
    atomicAdd(&q_rel_sum[b * 64 + o], tot);
  }
}

// ------------- w_row[b,t] = (SCALING/L) * dot(q_rel_sum[b,:], k_head[b,t,:]) -------------
__global__ __launch_bounds__(256) void wrow_kernel(
    const float* __restrict__ qkv, const float* __restrict__ q_rel_sum,
    float* __restrict__ w_row) {
  const int b = blockIdx.x;
  const int n = b >> 4, h = b & 15;
  __shared__ float q_s[64];
  if (threadIdx.x < 64)
    q_s[threadIdx.x] = q_rel_sum[b * 64 + threadIdx.x] * (SCALING / (float)L_SEQ);
  __syncthreads();
  for (int t = threadIdx.x; t < L_SEQ; t += 256) {
    const float* kp = &qkv[((size_t)(n * L_SEQ + t)) * (3 * D_EMB) + D_EMB + h * 64];
    float acc = 0.f;
    #pragma unroll
    for (int c = 0; c < 64; c += 4) {
      float4 kv = *(const float4*)&kp[c];
      acc += q_s[c] * kv.x + q_s[c + 1] * kv.y + q_s[c + 2] * kv.z + q_s[c + 3] * kv.w;
    }
    w_row[b * L_SEQ + t] = acc;
  }
}

// ------------- e[t]=exp(w[t]-max); inv[i]=1/prefix_sum(e) -------------
__global__ __launch_bounds__(256) void scan_kernel(
    const float* __restrict__ w_row, float* __restrict__ e_out,
    float* __restrict__ inv_out) {
  const int b = blockIdx.x;
  const int tid = threadIdx.x;
  __shared__ float sh[L_SEQ];
  __shared__ float ts[256];
  const float* wb = w_row + b * L_SEQ;
  float m = -3.4e38f;
  for (int i = tid; i < L_SEQ; i += 256) {
    float v = wb[i];
    sh[i] = v;
    m = fmaxf(m, v);
  }
  ts[tid] = m;
  __syncthreads();
  for (int off = 128; off > 0; off >>= 1) {
    if (tid < off) ts[tid] = fmaxf(ts[tid], ts[tid + off]);
    __syncthreads();
  }
  const float mx = ts[0];
  __syncthreads();
  const int t0 = tid * 8;
  float loc[8];
  float run = 0.f;
  #pragma unroll
  for (int k = 0; k < 8; ++k) {
    float ev = expf(sh[t0 + k] - mx);
    e_out[b * L_SEQ + t0 + k] = ev;
    run += ev;
    loc[k] = run;
  }
  ts[tid] = run;
  __syncthreads();
  for (int off = 1; off < 256; off <<= 1) {
    float v = ts[tid];
    float add = (tid >= off) ? ts[tid - off] : 0.f;
    __syncthreads();
    ts[tid] = v + add;
    __syncthreads();
  }
  float prefix = (tid > 0) ? ts[tid - 1] : 0.f;
  #pragma unroll
  for (int k = 0; k < 8; ++k) {
    inv_out[b * L_SEQ + t0 + k] = 1.f / (prefix + loc[k]);
  }
}

// ------------- causal Toeplitz conv via MFMA -------------
// attn_out[b,i,:] = inv[i] * sum_{j<=i} e[i-j] * v[b,j,:]
// grid (32 itiles, BHEADS), block 256 (4 waves). Wave w: rows i0+w*16..+15, cols 0..63.
// Per j-tile (64 rows): V staged transposed bf16 in LDS, e window reversed bf16.
__global__ __launch_bounds__(256) void conv_mfma_kernel(
    const float* __restrict__ qkv, const float* __restrict__ e_arr,
    const float* __restrict__ inv_arr, unsigned short* __restrict__ attn_out) {
  const int b = blockIdx.y;
  const int n = b >> 4, h = b & 15;
  const int i0 = blockIdx.x * 64;
  const int tid = threadIdx.x;
  const int lane = tid & 63;
  const int wave = tid >> 6;
  const int quad = lane >> 4;
  const int m = lane & 15;
  __shared__ unsigned short V_s[64][72];  // [col][j_local], stride 72 (16B-aligned rows)
  __shared__ unsigned short esr[128];     // reversed e window, bf16
  f32x4 acc[4] = {};
  const float* e_b = e_arr + b * L_SEQ;
  const float* vbase = qkv + 2 * (size_t)D_EMB + h * 64 + (size_t)n * L_SEQ * (3 * D_EMB);
  const int rrow = tid >> 4;            // 0..15 (staging row group)
  const int c4 = (tid & 15) << 2;       // col group
  for (int j0 = 0; j0 <= i0; j0 += 64) {
    // stage V[j0..j0+63][0..63] -> V_s[col][j] bf16 (transpose + convert)
    #pragma unroll
    for (int it = 0; it < 4; ++it) {
      const int jrow = rrow + it * 16;
      float4 v = *(const float4*)&vbase[(size_t)(j0 + jrow) * (3 * D_EMB) + c4];
      V_s[c4 + 0][jrow] = f2bf(v.x);
      V_s[c4 + 1][jrow] = f2bf(v.y);
      V_s[c4 + 2][jrow] = f2bf(v.z);
      V_s[c4 + 3][jrow] = f2bf(v.w);
    }
    // stage reversed e: esr[idx] = e[(i0-j0) + 64 - idx], 0 outside [0,L)
    if (tid < 128) {
      const int lag = (i0 - j0) + 64 - tid;
      const float ev = (lag >= 0 && lag < L_SEQ) ? e_b[lag] : 0.f;
      esr[tid] = f2bf(ev);
    }
    __syncthreads();
    #pragma unroll
    for (int k0 = 0; k0 < 64; k0 += 32) {
      // A-frag: A[m][k] = e[(i0+w*16+m) - (j0+k0+k)], lane m=lane&15, k=quad*8+jj
      const int s = 64 - (wave * 16 + m) + k0 + quad * 8;
      union { unsigned short u[8]; bf16x8 v; } au;
      #pragma unroll
      for (int jj = 0; jj < 8; ++jj) au.u[jj] = esr[s + jj];
      #pragma unroll
      for (int t = 0; t < 4; ++t) {
        const bf16x8 bfv = *(const bf16x8*)&V_s[t * 16 + m][k0 + quad * 8];
        acc[t] = __builtin_amdgcn_mfma_f32_16x16x32_bf16(au.v, bfv, acc[t], 0, 0, 0);
      }
    }
    __syncthreads();
  }
  // epilogue: D row = quad*4 + r, col = t*16 + m
  #pragma unroll
  for (int r = 0; r < 4; ++r) {
    const int i = i0 + wave * 16 + quad * 4 + r;
    const float iv = inv_arr[b * L_SEQ + i];
    unsigned short* op = &attn_out[((size_t)(n * L_SEQ + i)) * D_EMB + h * 64 + m];
    #pragma unroll
    for (int t = 0; t < 4; ++t) op[t * 16] = f2bf(acc[t][r] * iv);
  }
}

// ------------- wm[b,j] = (1/L) * sum_{d>=0, j+d<L} e[d]*inv[j+d] -------------
// grid (BHEADS, 16 j-chunks of 128), block 256: lane jj = tid&127, half h2 = tid>>7
__global__ __launch_bounds__(256) void wmean_kernel(
    const float* __restrict__ e_arr, const float* __restrict__ inv_arr,
    float* __restrict__ out_wm) {
  const int b = blockIdx.x;
  __shared__ float e_s[L_SEQ];
  __shared__ float inv_s[L_SEQ];
  __shared__ float red[256];
  const int tid = threadIdx.x;
  for (int i = tid; i < L_SEQ; i += 256) {
    e_s[i] = e_arr[b * L_SEQ + i];
    inv_s[i] = inv_arr[b * L_SEQ + i];
  }
  __syncthreads();
  const int jj = tid & 127;
  const int h2 = tid >> 7;
  const int j = blockIdx.y * 128 + jj;
  float acc = 0.f;
  for (int d = h2; j + d < L_SEQ; d += 2) acc += e_s[d] * inv_s[j + d];
  red[tid] = acc;
  __syncthreads();
  if (tid < 128)
    out_wm[b * L_SEQ + j] = (red[tid] + red[tid + 128]) * (1.f / (float)L_SEQ);
}

extern "C" void kernel_launch(void* const* d_in, const int* in_sizes, int n_in,
                              void* d_out, int out_size, void* d_ws, size_t ws_size,
                              hipStream_t stream) {
  const float* x       = (const float*)d_in[0];
  const float* W_in    = (const float*)d_in[1];
  const float* b_in    = (const float*)d_in[2];
  const float* Wc      = (const float*)d_in[3];
  const float* bc      = (const float*)d_in[4];
  const float* gamma   = (const float*)d_in[5];
  const float* beta    = (const float*)d_in[6];
  const float* W_out   = (const float*)d_in[7];
  const float* b_out   = (const float*)d_in[8];
  float* out = (float*)d_out;

  const int M = NBATCH * L_SEQ;      // 4096
  char* ws = (char*)d_ws;
  float* qkv            = (float*)ws;                                 // 50,331,648 B
  unsigned short* xa_bf = (unsigned short*)(ws + 50331648);           //  8,388,608 B (x_bf, later attn_bf)
  unsigned short* Win_bf= (unsigned short*)(ws + 50331648 + 8388608); //  6,291,456 B
  float* q_rel = (float*)(ws + 50331648 + 8388608 + 6291456);
  float* w_row = q_rel + BHEADS * HD;
  float* e_arr = w_row + BHEADS * L_SEQ;
  float* inv_a = e_arr + BHEADS * L_SEQ;
  unsigned short* Wout_bf = (unsigned short*)ws;                      // aliases dead qkv (after conv)

  hipMemsetAsync(q_rel, 0, BHEADS * HD * sizeof(float), stream);

  // 0) convert x and W_in to bf16
  cvt_bf16_kernel<<<dim3(M * D_EMB / 1024), 256, 0, stream>>>(x, xa_bf, M * D_EMB);
  cvt_bf16_kernel<<<dim3(3 * D_EMB * D_EMB / 1024), 256, 0, stream>>>(W_in, Win_bf, 3 * D_EMB * D_EMB);
  // 1) qkv = x @ W_in^T + b_in   (bf16 MFMA, fp32 out)
  gemm_bt_bf16<<<dim3(3 * D_EMB / 128, M / 128), 256, 0, stream>>>(
      xa_bf, Win_bf, b_in, qkv, M, 3 * D_EMB, D_EMB);
  // 2) q_temp -> q_rel sums
  qtemp_qrel_kernel<<<dim3(BHEADS, 16), 256, 0, stream>>>(
      qkv, Wc, bc, gamma, beta, q_rel);
  // 3) w_row
  wrow_kernel<<<dim3(BHEADS), 256, 0, stream>>>(qkv, q_rel, w_row);
  // 4) softmax scan
  scan_kernel<<<dim3(BHEADS), 256, 0, stream>>>(w_row, e_arr, inv_a);
  // 5) causal Toeplitz conv via MFMA -> attn bf16 (into x_bf region)
  conv_mfma_kernel<<<dim3(L_SEQ / 64, BHEADS), 256, 0, stream>>>(qkv, e_arr, inv_a, xa_bf);
  // 6) convert W_out (into dead qkv region)
  cvt_bf16_kernel<<<dim3(D_EMB * D_EMB / 1024), 256, 0, stream>>>(W_out, Wout_bf, D_EMB * D_EMB);
  // 7) weights.mean(axis=1) -> second output
  wmean_kernel<<<dim3(BHEADS, L_SEQ / 128), 256, 0, stream>>>(
      e_arr, inv_a, out + (size_t)M * D_EMB);
  // 8) output = attn @ W_out^T + b_out  (bf16 MFMA, fp32 out)
  gemm_bt_bf16<<<dim3(D_EMB / 128, M / 128), 256, 0, stream>>>(
      xa_bf, Wout_bf, b_out, out, M, D_EMB, D_EMB);
}

// Round 4
// 346.423 us; speedup vs baseline: 3.0178x; 1.1393x over previous
//
#include <hip/hip_runtime.h>
#include <math.h>

#define L_SEQ 2048
#define D_EMB 1024
#define NHEADS 16
#define HD 64
#define BHEADS 32   // N*NHEADS
#define NBATCH 2
#define LN_EPS 1e-5f
#define SCALING 0.125f

typedef __attribute__((ext_vector_type(8))) __bf16 bf16x8;
typedef __attribute__((ext_vector_type(4))) float f32x4;
typedef const __attribute__((address_space(1))) unsigned int* gptr_as1;
typedef __attribute__((address_space(3))) unsigned int* lptr_as3;

__device__ __forceinline__ void load16_to_lds(const void* g, void* l) {
  __builtin_amdgcn_global_load_lds((gptr_as1)g, (lptr_as3)l, 16, 0, 0);
}

__device__ __forceinline__ unsigned short f2bf(float f) {
  unsigned int u = __float_as_uint(f);
  u += 0x7fff + ((u >> 16) & 1);   // round-to-nearest-even
  return (unsigned short)(u >> 16);
}

// ---------------- fp32 -> bf16 convert (RNE), 4 elems/thread ----------------
__global__ __launch_bounds__(256) void cvt_bf16_kernel(
    const float* __restrict__ in, unsigned short* __restrict__ out, int n) {
  int i = (blockIdx.x * 256 + threadIdx.x) * 4;
  if (i < n) {
    float4 v = *(const float4*)&in[i];
    ushort4 o;
    o.x = f2bf(v.x); o.y = f2bf(v.y); o.z = f2bf(v.z); o.w = f2bf(v.w);
    *(ushort4*)&out[i] = o;
  }
}

// ---------------- bf16 MFMA GEMM: C_f32 = A @ B^T + bias ----------------
__global__ __launch_bounds__(256) void gemm_bt_bf16(
    const unsigned short* __restrict__ A, const unsigned short* __restrict__ B,
    const float* __restrict__ bias, float* __restrict__ C,
    int M, int Nn, int K) {
  __shared__ unsigned short As[4096];   // 128x32 bf16, fragment-major
  __shared__ unsigned short Bs[4096];
  const int bm = blockIdx.y * 128;
  const int bn = blockIdx.x * 128;
  const int tid = threadIdx.x;
  const int lane = tid & 63;
  const int wave = tid >> 6;
  const int wr = (wave >> 1) * 64;
  const int wc = (wave & 1) * 64;

  const int c0 = tid, c1 = tid + 256;
  const unsigned short* ga0 = A + (size_t)(bm + (c0 >> 6) * 16 + (c0 & 15)) * K + ((c0 >> 4) & 3) * 8;
  const unsigned short* ga1 = A + (size_t)(bm + (c1 >> 6) * 16 + (c1 & 15)) * K + ((c1 >> 4) & 3) * 8;
  const unsigned short* gb0 = B + (size_t)(bn + (c0 >> 6) * 16 + (c0 & 15)) * K + ((c0 >> 4) & 3) * 8;
  const unsigned short* gb1 = B + (size_t)(bn + (c1 >> 6) * 16 + (c1 & 15)) * K + ((c1 >> 4) & 3) * 8;
  unsigned short* la0 = &As[c0 * 8];
  unsigned short* la1 = &As[c1 * 8];
  unsigned short* lb0 = &Bs[c0 * 8];
  unsigned short* lb1 = &Bs[c1 * 8];

  f32x4 acc[4][4] = {};
  for (int k0 = 0; k0 < K; k0 += 32) {
    load16_to_lds(ga0 + k0, la0);
    load16_to_lds(ga1 + k0, la1);
    load16_to_lds(gb0 + k0, lb0);
    load16_to_lds(gb1 + k0, lb1);
    __syncthreads();
    bf16x8 af[4], bf[4];
    #pragma unroll
    for (int i = 0; i < 4; ++i)
      af[i] = *(const bf16x8*)&As[((wr >> 4) + i) * 512 + lane * 8];
    #pragma unroll
    for (int j = 0; j < 4; ++j)
      bf[j] = *(const bf16x8*)&Bs[((wc >> 4) + j) * 512 + lane * 8];
    #pragma unroll
    for (int i = 0; i < 4; ++i)
      #pragma unroll
      for (int j = 0; j < 4; ++j)
        acc[i][j] = __builtin_amdgcn_mfma_f32_16x16x32_bf16(af[i], bf[j], acc[i][j], 0, 0, 0);
    __syncthreads();
  }
  const int lc = lane & 15;
  const int lr4 = (lane >> 4) * 4;
  float bv[4];
  #pragma unroll
  for (int j = 0; j < 4; ++j) bv[j] = bias[bn + wc + j * 16 + lc];
  #pragma unroll
  for (int i = 0; i < 4; ++i) {
    #pragma unroll
    for (int r = 0; r < 4; ++r) {
      const int row = bm + wr + i * 16 + lr4 + r;
      float* cp = &C[(size_t)row * Nn + bn + wc + lc];
      #pragma unroll
      for (int j = 0; j < 4; ++j) cp[j * 16] = acc[i][j][r] + bv[j];
    }
  }
}

// ------------- q_temp = LN(gelu(q_head @ Wc^T + bc)); q_rel_sum = sum_l q_temp -------------
__global__ __launch_bounds__(256) void qtemp_qrel_kernel(
    const float* __restrict__ qkv, const float* __restrict__ Wc,
    const float* __restrict__ bc, const float* __restrict__ gamma,
    const float* __restrict__ beta, float* __restrict__ q_rel_sum) {
  __shared__ float Wc_s[64][65];
  __shared__ float q_s[4][64];
  __shared__ float red[4][64];
  const int b = blockIdx.x;
  const int n = b >> 4, h = b & 15;
  const int tid = threadIdx.x;
  const int wave = tid >> 6;
  const int o = tid & 63;
  for (int i = tid; i < 64 * 64; i += 256) Wc_s[i >> 6][i & 63] = Wc[i];
  __syncthreads();
  const float bco = bc[o];
  const float go = gamma[o];
  const float bo = beta[o];
  float accum = 0.f;
  const int l0 = blockIdx.y * 128 + wave * 32;
  for (int li = 0; li < 32; ++li) {
    const int l = l0 + li;
    q_s[wave][o] = qkv[((size_t)(n * L_SEQ + l)) * (3 * D_EMB) + h * 64 + o];
    float dot = bco;
    #pragma unroll
    for (int c = 0; c < 64; ++c) dot += q_s[wave][c] * Wc_s[o][c];
    float g = 0.5f * dot * (1.f + erff(dot * 0.70710678118654752f));
    float s1 = g, s2 = g * g;
    #pragma unroll
    for (int off = 32; off > 0; off >>= 1) {
      s1 += __shfl_xor(s1, off);
      s2 += __shfl_xor(s2, off);
    }
    float mu = s1 * (1.f / 64.f);
    float var = s2 * (1.f / 64.f) - mu * mu;
    float y = (g - mu) * rsqrtf(var + LN_EPS) * go + bo;
    accum += y;
  }
  red[wave][o] = accum;
  __syncthreads();
  if (wave == 0) {
    float tot = red[0][o] + red[1][o] + red[2][o] + red[3][o];
    atomicAdd(&q_rel_sum[b * 64 + o], tot);
  }
}

// ------------- w_row[b,t] = (SCALING/L) * dot(q_rel_sum[b,:], k_head[b,t,:]) -------------
__global__ __launch_bounds__(256) void wrow_kernel(
    const float* __restrict__ qkv, const float* __restrict__ q_rel_sum,
    float* __restrict__ w_row) {
  const int b = blockIdx.x;
  const int n = b >> 4, h = b & 15;
  __shared__ float q_s[64];
  if (threadIdx.x < 64)
    q_s[threadIdx.x] = q_rel_sum[b * 64 + threadIdx.x] * (SCALING / (float)L_SEQ);
  __syncthreads();
  for (int t = threadIdx.x; t < L_SEQ; t += 256) {
    const float* kp = &qkv[((size_t)(n * L_SEQ + t)) * (3 * D_EMB) + D_EMB + h * 64];
    float acc = 0.f;
    #pragma unroll
    for (int c = 0; c < 64; c += 4) {
      float4 kv = *(const float4*)&kp[c];
      acc += q_s[c] * kv.x + q_s[c + 1] * kv.y + q_s[c + 2] * kv.z + q_s[c + 3] * kv.w;
    }
    w_row[b * L_SEQ + t] = acc;
  }
}

// ------------- e[t]=exp(w[t]-max); inv[i]=1/prefix_sum(e) -------------
__global__ __launch_bounds__(256) void scan_kernel(
    const float* __restrict__ w_row, float* __restrict__ e_out,
    float* __restrict__ inv_out) {
  const int b = blockIdx.x;
  const int tid = threadIdx.x;
  __shared__ float sh[L_SEQ];
  __shared__ float ts[256];
  const float* wb = w_row + b * L_SEQ;
  float m = -3.4e38f;
  for (int i = tid; i < L_SEQ; i += 256) {
    float v = wb[i];
    sh[i] = v;
    m = fmaxf(m, v);
  }
  ts[tid] = m;
  __syncthreads();
  for (int off = 128; off > 0; off >>= 1) {
    if (tid < off) ts[tid] = fmaxf(ts[tid], ts[tid + off]);
    __syncthreads();
  }
  const float mx = ts[0];
  __syncthreads();
  const int t0 = tid * 8;
  float loc[8];
  float run = 0.f;
  #pragma unroll
  for (int k = 0; k < 8; ++k) {
    float ev = expf(sh[t0 + k] - mx);
    e_out[b * L_SEQ + t0 + k] = ev;
    run += ev;
    loc[k] = run;
  }
  ts[tid] = run;
  __syncthreads();
  for (int off = 1; off < 256; off <<= 1) {
    float v = ts[tid];
    float add = (tid >= off) ? ts[tid - off] : 0.f;
    __syncthreads();
    ts[tid] = v + add;
    __syncthreads();
  }
  float prefix = (tid > 0) ? ts[tid - 1] : 0.f;
  #pragma unroll
  for (int k = 0; k < 8; ++k) {
    inv_out[b * L_SEQ + t0 + k] = 1.f / (prefix + loc[k]);
  }
}

// ------------- V transpose: vT[b][d][j] = bf16(V[b][j][d]) -------------
// grid (32 j-tiles, 32 heads), block 256
__global__ __launch_bounds__(256) void transpose_v_kernel(
    const float* __restrict__ qkv, unsigned short* __restrict__ vT) {
  __shared__ unsigned short Vt_s[64][80];   // stride 80 u16 = 160 B (16B-mult)
  const int jt = blockIdx.x;
  const int b = blockIdx.y;
  const int n = b >> 4, h = b & 15;
  const int j0 = jt * 64;
  const int tid = threadIdx.x;
  const int rr = tid >> 4;
  const int c4 = (tid & 15) << 2;
  const float* vbase = qkv + (size_t)n * L_SEQ * (3 * D_EMB) + 2 * D_EMB + h * 64;
  #pragma unroll
  for (int it = 0; it < 4; ++it) {
    const int jrow = rr + it * 16;
    float4 v = *(const float4*)&vbase[(size_t)(j0 + jrow) * (3 * D_EMB) + c4];
    Vt_s[c4 + 0][jrow] = f2bf(v.x);
    Vt_s[c4 + 1][jrow] = f2bf(v.y);
    Vt_s[c4 + 2][jrow] = f2bf(v.z);
    Vt_s[c4 + 3][jrow] = f2bf(v.w);
  }
  __syncthreads();
  #pragma unroll
  for (int cc = 0; cc < 2; ++cc) {
    const int c = tid + cc * 256;
    const int d = c >> 3;
    const int q = c & 7;
    uint4 val = *(const uint4*)&Vt_s[d][q * 8];
    *(uint4*)&vT[(size_t)(b * 64 + d) * L_SEQ + j0 + q * 8] = val;
  }
}

// ------------- causal Toeplitz conv via MFMA, 256 i-rows per block -------------
// attn_out[b,i,:] = inv[i] * sum_{j<=i} e[i-j] * vT[d][j]
// grid (8 i-bands, 32 heads), 4 waves; wave w owns rows [blkI + w*64, +64).
// LDS: fragment-major vT tile (64 d x 64 j), 8 shift-replicated reversed-e rows,
// both double-buffered; A-frag = 1 aligned ds_read_b128 via replica r = s&7.
__global__ __launch_bounds__(256) void conv_mfma_kernel(
    const unsigned short* __restrict__ vT, const float* __restrict__ e_arr,
    const float* __restrict__ inv_arr, unsigned short* __restrict__ attn_out) {
  __shared__ unsigned short V_s[2][4096];   // 512 chunks of 16B, fragment-major
  __shared__ unsigned short rep[2][8 * 320];
  const int blk = 7 - blockIdx.x;           // heavy blocks first
  const int b = blockIdx.y;
  const int n = b >> 4, h = b & 15;
  const int blkI = blk * 256;
  const int blk4 = blk * 4;
  const int njt = blk4 + 4;
  const int tid = threadIdx.x;
  const int lane = tid & 63;
  const int wave = tid >> 6;
  const int quad = lane >> 4;
  const int mi = lane & 15;
  const float* e_b = e_arr + b * L_SEQ;

  // staging sources (chunk c: d=(c>>7)*16+(c&15), q=(c>>4)&7)
  const int c0 = tid, c1 = tid + 256;
  const unsigned short* vsrc0 = vT + (size_t)(b * 64 + (c0 >> 7) * 16 + (c0 & 15)) * L_SEQ + ((c0 >> 4) & 7) * 8;
  const unsigned short* vsrc1 = vT + (size_t)(b * 64 + (c1 >> 7) * 16 + (c1 & 15)) * L_SEQ + ((c1 >> 4) & 7) * 8;

  f32x4 acc[4][4] = {};

  // ---- stage(jt=0, buf=0) ----
  {
    load16_to_lds(vsrc0, &V_s[0][c0 * 8]);
    load16_to_lds(vsrc1, &V_s[0][c1 * 8]);
    const int lagBase = blkI;
    int v = tid;
    int lag = lagBase + 256 - v;
    float ev = (lag >= 0 && lag < L_SEQ) ? e_b[lag] : 0.f;
    unsigned short bfv = f2bf(ev);
    #pragma unroll
    for (int r = 0; r < 8; ++r) { int idx = v - r; if (idx >= 0) rep[0][r * 320 + idx] = bfv; }
    if (tid < 64) {
      v = tid + 256;
      lag = lagBase - tid;
      ev = (lag >= 0 && lag < L_SEQ) ? e_b[lag] : 0.f;
      bfv = f2bf(ev);
      #pragma unroll
      for (int r = 0; r < 8; ++r) rep[0][r * 320 + (v - r)] = bfv;
    }
  }

  for (int jt = 0; jt < njt; ++jt) {
    __syncthreads();
    const int cb = jt & 1;
    if (jt + 1 < njt) {      // prefetch next tile into the other buffer
      const int pb = cb ^ 1;
      const int j0 = (jt + 1) * 64;
      load16_to_lds(vsrc0 + j0, &V_s[pb][c0 * 8]);
      load16_to_lds(vsrc1 + j0, &V_s[pb][c1 * 8]);
      const int lagBase = blkI - j0;
      int v = tid;
      int lag = lagBase + 256 - v;
      float ev = (lag >= 0 && lag < L_SEQ) ? e_b[lag] : 0.f;
      unsigned short bfv = f2bf(ev);
      #pragma unroll
      for (int r = 0; r < 8; ++r) { int idx = v - r; if (idx >= 0) rep[pb][r * 320 + idx] = bfv; }
      if (tid < 64) {
        v = tid + 256;
        lag = lagBase - tid;
        ev = (lag >= 0 && lag < L_SEQ) ? e_b[lag] : 0.f;
        bfv = f2bf(ev);
        #pragma unroll
        for (int r = 0; r < 8; ++r) rep[pb][r * 320 + (v - r)] = bfv;
      }
    }
    if (jt <= blk4 + wave) {
      const unsigned short* Vb = V_s[cb];
      const unsigned short* Rb = rep[cb];
      // 6 unique A-frags: q' = isub - 2*(k0/32) in [-2,3]
      bf16x8 ef[6];
      #pragma unroll
      for (int q = 0; q < 6; ++q) {
        const int s = 256 - wave * 64 - mi + quad * 8 - 16 * (q - 2);
        const int rr = s & 7;
        ef[q] = *(const bf16x8*)&Rb[rr * 320 + (s - rr)];
      }
      #pragma unroll
      for (int kk = 0; kk < 2; ++kk) {
        bf16x8 bv[4];
        #pragma unroll
        for (int t = 0; t < 4; ++t)
          bv[t] = *(const bf16x8*)&Vb[t * 1024 + kk * 512 + lane * 8];
        #pragma unroll
        for (int isub = 0; isub < 4; ++isub) {
          const int qi = isub - 2 * kk + 2;
          #pragma unroll
          for (int t = 0; t < 4; ++t)
            acc[isub][t] = __builtin_amdgcn_mfma_f32_16x16x32_bf16(ef[qi], bv[t], acc[isub][t], 0, 0, 0);
        }
      }
    }
  }
  // epilogue: D col = t*16+mi, row = quad*4 + r within 16-row isub tile
  #pragma unroll
  for (int isub = 0; isub < 4; ++isub) {
    #pragma unroll
    for (int r = 0; r < 4; ++r) {
      const int i = blkI + wave * 64 + isub * 16 + quad * 4 + r;
      const float iv = inv_arr[b * L_SEQ + i];
      unsigned short* op = &attn_out[((size_t)(n * L_SEQ + i)) * D_EMB + h * 64 + mi];
      #pragma unroll
      for (int t = 0; t < 4; ++t) op[t * 16] = f2bf(acc[isub][t][r] * iv);
    }
  }
}

// ------------- wm[b,j] = (1/L) * sum_{d>=0, j+d<L} e[d]*inv[j+d] -------------
__global__ __launch_bounds__(256) void wmean_kernel(
    const float* __restrict__ e_arr, const float* __restrict__ inv_arr,
    float* __restrict__ out_wm) {
  const int b = blockIdx.x;
  __shared__ float e_s[L_SEQ];
  __shared__ float inv_s[L_SEQ];
  __shared__ float red[256];
  const int tid = threadIdx.x;
  for (int i = tid; i < L_SEQ; i += 256) {
    e_s[i] = e_arr[b * L_SEQ + i];
    inv_s[i] = inv_arr[b * L_SEQ + i];
  }
  __syncthreads();
  const int jj = tid & 127;
  const int h2 = tid >> 7;
  const int j = blockIdx.y * 128 + jj;
  float acc = 0.f;
  for (int d = h2; j + d < L_SEQ; d += 2) acc += e_s[d] * inv_s[j + d];
  red[tid] = acc;
  __syncthreads();
  if (tid < 128)
    out_wm[b * L_SEQ + j] = (red[tid] + red[tid + 128]) * (1.f / (float)L_SEQ);
}

extern "C" void kernel_launch(void* const* d_in, const int* in_sizes, int n_in,
                              void* d_out, int out_size, void* d_ws, size_t ws_size,
                              hipStream_t stream) {
  const float* x       = (const float*)d_in[0];
  const float* W_in    = (const float*)d_in[1];
  const float* b_in    = (const float*)d_in[2];
  const float* Wc      = (const float*)d_in[3];
  const float* bc      = (const float*)d_in[4];
  const float* gamma   = (const float*)d_in[5];
  const float* beta    = (const float*)d_in[6];
  const float* W_out   = (const float*)d_in[7];
  const float* b_out   = (const float*)d_in[8];
  float* out = (float*)d_out;

  const int M = NBATCH * L_SEQ;      // 4096
  char* ws = (char*)d_ws;
  float* qkv            = (float*)ws;                                 // 50,331,648 B
  unsigned short* xa_bf = (unsigned short*)(ws + 50331648);           //  8,388,608 B (x_bf, later attn_bf)
  unsigned short* Win_bf= (unsigned short*)(ws + 50331648 + 8388608); //  6,291,456 B
  float* q_rel = (float*)(ws + 50331648 + 8388608 + 6291456);
  float* w_row = q_rel + BHEADS * HD;
  float* e_arr = w_row + BHEADS * L_SEQ;
  float* inv_a = e_arr + BHEADS * L_SEQ;
  unsigned short* Wout_bf = (unsigned short*)ws;                      // aliases dead qkv (after conv)
  // vT scratch lives in d_out's output-0 region (8.4 MB < 16.8 MB);
  // fully consumed by conv before the final GEMM overwrites output 0.
  unsigned short* vT = (unsigned short*)d_out;

  hipMemsetAsync(q_rel, 0, BHEADS * HD * sizeof(float), stream);

  // 0) convert x and W_in to bf16
  cvt_bf16_kernel<<<dim3(M * D_EMB / 1024), 256, 0, stream>>>(x, xa_bf, M * D_EMB);
  cvt_bf16_kernel<<<dim3(3 * D_EMB * D_EMB / 1024), 256, 0, stream>>>(W_in, Win_bf, 3 * D_EMB * D_EMB);
  // 1) qkv = x @ W_in^T + b_in   (bf16 MFMA, fp32 out)
  gemm_bt_bf16<<<dim3(3 * D_EMB / 128, M / 128), 256, 0, stream>>>(
      xa_bf, Win_bf, b_in, qkv, M, 3 * D_EMB, D_EMB);
  // 1b) transpose V -> vT bf16 (in d_out scratch)
  transpose_v_kernel<<<dim3(L_SEQ / 64, BHEADS), 256, 0, stream>>>(qkv, vT);
  // 2) q_temp -> q_rel sums
  qtemp_qrel_kernel<<<dim3(BHEADS, 16), 256, 0, stream>>>(
      qkv, Wc, bc, gamma, beta, q_rel);
  // 3) w_row
  wrow_kernel<<<dim3(BHEADS), 256, 0, stream>>>(qkv, q_rel, w_row);
  // 4) softmax scan
  scan_kernel<<<dim3(BHEADS), 256, 0, stream>>>(w_row, e_arr, inv_a);
  // 5) causal Toeplitz conv via MFMA -> attn bf16 (into x_bf region)
  conv_mfma_kernel<<<dim3(8, BHEADS), 256, 0, stream>>>(vT, e_arr, inv_a, xa_bf);
  // 6) convert W_out (into dead qkv region)
  cvt_bf16_kernel<<<dim3(D_EMB * D_EMB / 1024), 256, 0, stream>>>(W_out, Wout_bf, D_EMB * D_EMB);
  // 7) weights.mean(axis=1) -> second output
  wmean_kernel<<<dim3(BHEADS, L_SEQ / 128), 256, 0, stream>>>(
      e_arr, inv_a, out + (size_t)M * D_EMB);
  // 8) output = attn @ W_out^T + b_out  (bf16 MFMA, fp32 out; overwrites vT scratch)
  gemm_bt_bf16<<<dim3(D_EMB / 128, M / 128), 256, 0, stream>>>(
      xa_bf, Wout_bf, b_out, out, M, D_EMB, D_EMB);
}

// Round 5
// 334.989 us; speedup vs baseline: 3.1208x; 1.0341x over previous
//
#include <hip/hip_runtime.h>
#include <math.h>

#define L_SEQ 2048
#define D_EMB 1024
#define NHEADS 16
#define HD 64
#define BHEADS 32   // N*NHEADS
#define NBATCH 2
#define LN_EPS 1e-5f
#define SCALING 0.125f

typedef __attribute__((ext_vector_type(8))) __bf16 bf16x8;
typedef __attribute__((ext_vector_type(4))) float f32x4;
typedef const __attribute__((address_space(1))) unsigned int* gptr_as1;
typedef __attribute__((address_space(3))) unsigned int* lptr_as3;

__device__ __forceinline__ void load16_to_lds(const void* g, void* l) {
  __builtin_amdgcn_global_load_lds((gptr_as1)g, (lptr_as3)l, 16, 0, 0);
}

__device__ __forceinline__ unsigned short f2bf(float f) {
  unsigned int u = __float_as_uint(f);
  u += 0x7fff + ((u >> 16) & 1);   // round-to-nearest-even
  return (unsigned short)(u >> 16);
}

__device__ __forceinline__ float bf2f(unsigned short us) {
  return __uint_as_float((unsigned int)us << 16);
}

// ---------------- fp32 -> bf16 convert (RNE), 4 elems/thread ----------------
__global__ __launch_bounds__(256) void cvt_bf16_kernel(
    const float* __restrict__ in, unsigned short* __restrict__ out, int n) {
  int i = (blockIdx.x * 256 + threadIdx.x) * 4;
  if (i < n) {
    float4 v = *(const float4*)&in[i];
    ushort4 o;
    o.x = f2bf(v.x); o.y = f2bf(v.y); o.z = f2bf(v.z); o.w = f2bf(v.w);
    *(ushort4*)&out[i] = o;
  }
}

// ---------------- two-tensor fp32 -> bf16 convert ----------------
__global__ __launch_bounds__(256) void cvt2_bf16_kernel(
    const float* __restrict__ a, int na, const float* __restrict__ b, int nb,
    unsigned short* __restrict__ oa, unsigned short* __restrict__ ob) {
  int i = (blockIdx.x * 256 + threadIdx.x) * 4;
  if (i < na) {
    float4 v = *(const float4*)&a[i];
    ushort4 o;
    o.x = f2bf(v.x); o.y = f2bf(v.y); o.z = f2bf(v.z); o.w = f2bf(v.w);
    *(ushort4*)&oa[i] = o;
  } else {
    int j = i - na;
    if (j < nb) {
      float4 v = *(const float4*)&b[j];
      ushort4 o;
      o.x = f2bf(v.x); o.y = f2bf(v.y); o.z = f2bf(v.z); o.w = f2bf(v.w);
      *(ushort4*)&ob[j] = o;
    }
  }
}

// ---------------- bf16 MFMA GEMM, BK=64: C = A @ B^T + bias ----------------
// A: M x K row-major bf16, B: N x K row-major bf16.
// QKV=false: C fp32 row-major (stride Nn).
// QKV=true : cols < 2048 -> bf16 C (stride Nn); cols >= 2048 (v) -> transposed
//            bf16 write into vT[(n*16+h)*64+d][j] (ushort4 along j).
// 128x128 tile, 4 waves (2x2 of 64x64), fragment-major LDS, lane-linear staging.
template<bool QKV>
__global__ __launch_bounds__(256) void gemm_bt64(
    const unsigned short* __restrict__ A, const unsigned short* __restrict__ B,
    const float* __restrict__ bias, void* __restrict__ Cout,
    unsigned short* __restrict__ vT, int M, int Nn, int K) {
  __shared__ unsigned short As[8192];   // 128 x 64 bf16, fragment-major
  __shared__ unsigned short Bs[8192];
  const int bm = blockIdx.y * 128;
  const int bn = blockIdx.x * 128;
  const int tid = threadIdx.x;
  const int lane = tid & 63;
  const int wave = tid >> 6;
  const int wr = (wave >> 1) * 64;
  const int wc = (wave & 1) * 64;

  const unsigned short* ga[4];
  const unsigned short* gb[4];
  int lofs[4];
  #pragma unroll
  for (int s = 0; s < 4; ++s) {
    const int c = tid + s * 256;
    const int row = ((c >> 7) << 4) + (c & 15);
    const int kof = ((c >> 4) & 7) << 3;
    ga[s] = A + (size_t)(bm + row) * K + kof;
    gb[s] = B + (size_t)(bn + row) * K + kof;
    lofs[s] = c * 8;
  }

  f32x4 acc[4][4] = {};
  for (int k0 = 0; k0 < K; k0 += 64) {
    #pragma unroll
    for (int s = 0; s < 4; ++s) load16_to_lds(ga[s] + k0, &As[lofs[s]]);
    #pragma unroll
    for (int s = 0; s < 4; ++s) load16_to_lds(gb[s] + k0, &Bs[lofs[s]]);
    __syncthreads();
    #pragma unroll
    for (int kk = 0; kk < 2; ++kk) {
      const int kof = (kk * 4 + (lane >> 4)) * 128 + (lane & 15) * 8;
      bf16x8 af[4], bf[4];
      #pragma unroll
      for (int i = 0; i < 4; ++i)
        af[i] = *(const bf16x8*)&As[((wr >> 4) + i) * 1024 + kof];
      #pragma unroll
      for (int j = 0; j < 4; ++j)
        bf[j] = *(const bf16x8*)&Bs[((wc >> 4) + j) * 1024 + kof];
      #pragma unroll
      for (int i = 0; i < 4; ++i)
        #pragma unroll
        for (int j = 0; j < 4; ++j)
          acc[i][j] = __builtin_amdgcn_mfma_f32_16x16x32_bf16(af[i], bf[j], acc[i][j], 0, 0, 0);
    }
    __syncthreads();
  }
  // epilogue: D layout col=lane&15, row=(lane>>4)*4+reg
  const int lc = lane & 15;
  const int lr4 = (lane >> 4) << 2;
  float bv[4];
  #pragma unroll
  for (int j = 0; j < 4; ++j) bv[j] = bias[bn + wc + j * 16 + lc];
  if (!QKV) {
    float* C = (float*)Cout;
    #pragma unroll
    for (int i = 0; i < 4; ++i)
      #pragma unroll
      for (int r = 0; r < 4; ++r) {
        const int row = bm + wr + i * 16 + lr4 + r;
        float* cp = &C[(size_t)row * Nn + bn + wc + lc];
        #pragma unroll
        for (int j = 0; j < 4; ++j) cp[j * 16] = acc[i][j][r] + bv[j];
      }
  } else if (bn < 2 * D_EMB) {
    unsigned short* C = (unsigned short*)Cout;
    #pragma unroll
    for (int i = 0; i < 4; ++i)
      #pragma unroll
      for (int r = 0; r < 4; ++r) {
        const int row = bm + wr + i * 16 + lr4 + r;
        unsigned short* cp = &C[(size_t)row * Nn + bn + wc + lc];
        #pragma unroll
        for (int j = 0; j < 4; ++j) cp[j * 16] = f2bf(acc[i][j][r] + bv[j]);
      }
  } else {
    // v block: transposed write into vT (4 consecutive rows = ushort4 along j)
    #pragma unroll
    for (int i = 0; i < 4; ++i) {
      const int row0 = bm + wr + i * 16 + lr4;
      const int n = row0 >> 11;
      const int jseq = row0 & (L_SEQ - 1);
      #pragma unroll
      for (int j = 0; j < 4; ++j) {
        const int col = bn + wc + j * 16 + lc;
        const int d = col & 63;
        const int h = (col >> 6) & 15;
        ushort4 o;
        o.x = f2bf(acc[i][j][0] + bv[j]);
        o.y = f2bf(acc[i][j][1] + bv[j]);
        o.z = f2bf(acc[i][j][2] + bv[j]);
        o.w = f2bf(acc[i][j][3] + bv[j]);
        *(ushort4*)&vT[(size_t)((n * 16 + h) * 64 + d) * L_SEQ + jseq] = o;
      }
    }
  }
}

// ------------- q_temp = LN(gelu(q_head @ Wc^T + bc)); q_rel_sum = sum_l q_temp -------------
__global__ __launch_bounds__(256) void qtemp_qrel_kernel(
    const unsigned short* __restrict__ qkv_bf, const float* __restrict__ Wc,
    const float* __restrict__ bc, const float* __restrict__ gamma,
    const float* __restrict__ beta, float* __restrict__ q_rel_sum) {
  __shared__ float Wc_s[64][65];
  __shared__ float q_s[4][64];
  __shared__ float red[4][64];
  const int b = blockIdx.x;
  const int n = b >> 4, h = b & 15;
  const int tid = threadIdx.x;
  const int wave = tid >> 6;
  const int o = tid & 63;
  for (int i = tid; i < 64 * 64; i += 256) Wc_s[i >> 6][i & 63] = Wc[i];
  __syncthreads();
  const float bco = bc[o];
  const float go = gamma[o];
  const float bo = beta[o];
  float accum = 0.f;
  const int l0 = blockIdx.y * 128 + wave * 32;
  for (int li = 0; li < 32; ++li) {
    const int l = l0 + li;
    q_s[wave][o] = bf2f(qkv_bf[(size_t)(n * L_SEQ + l) * (3 * D_EMB) + h * 64 + o]);
    float dot = bco;
    #pragma unroll
    for (int c = 0; c < 64; ++c) dot += q_s[wave][c] * Wc_s[o][c];
    float g = 0.5f * dot * (1.f + erff(dot * 0.70710678118654752f));
    float s1 = g, s2 = g * g;
    #pragma unroll
    for (int off = 32; off > 0; off >>= 1) {
      s1 += __shfl_xor(s1, off);
      s2 += __shfl_xor(s2, off);
    }
    float mu = s1 * (1.f / 64.f);
    float var = s2 * (1.f / 64.f) - mu * mu;
    float y = (g - mu) * rsqrtf(var + LN_EPS) * go + bo;
    accum += y;
  }
  red[wave][o] = accum;
  __syncthreads();
  if (wave == 0) {
    float tot = red[0][o] + red[1][o] + red[2][o] + red[3][o];
    atomicAdd(&q_rel_sum[b * 64 + o], tot);
  }
}

// ------------- fused: w_row -> max -> exp -> prefix-scan -> e, inv -------------
__global__ __launch_bounds__(256) void wrow_scan_kernel(
    const unsigned short* __restrict__ qkv_bf, const float* __restrict__ q_rel_sum,
    float* __restrict__ e_out, float* __restrict__ inv_out) {
  const int b = blockIdx.x;
  const int n = b >> 4, h = b & 15;
  const int tid = threadIdx.x;
  __shared__ float q_s[64];
  __shared__ float sh[L_SEQ];
  __shared__ float ts[256];
  if (tid < 64) q_s[tid] = q_rel_sum[b * 64 + tid] * (SCALING / (float)L_SEQ);
  __syncthreads();
  float m = -3.4e38f;
  for (int it = 0; it < 8; ++it) {
    const int t = it * 256 + tid;
    const unsigned short* kp = &qkv_bf[(size_t)(n * L_SEQ + t) * (3 * D_EMB) + D_EMB + h * 64];
    float acc = 0.f;
    #pragma unroll
    for (int c = 0; c < 64; c += 8) {
      uint4 kv = *(const uint4*)&kp[c];
      acc += q_s[c + 0] * __uint_as_float(kv.x << 16);
      acc += q_s[c + 1] * __uint_as_float(kv.x & 0xffff0000u);
      acc += q_s[c + 2] * __uint_as_float(kv.y << 16);
      acc += q_s[c + 3] * __uint_as_float(kv.y & 0xffff0000u);
      acc += q_s[c + 4] * __uint_as_float(kv.z << 16);
      acc += q_s[c + 5] * __uint_as_float(kv.z & 0xffff0000u);
      acc += q_s[c + 6] * __uint_as_float(kv.w << 16);
      acc += q_s[c + 7] * __uint_as_float(kv.w & 0xffff0000u);
    }
    sh[t] = acc;
    m = fmaxf(m, acc);
  }
  ts[tid] = m;
  __syncthreads();
  for (int off = 128; off > 0; off >>= 1) {
    if (tid < off) ts[tid] = fmaxf(ts[tid], ts[tid + off]);
    __syncthreads();
  }
  const float mx = ts[0];
  __syncthreads();
  const int t0 = tid * 8;
  float loc[8];
  float run = 0.f;
  #pragma unroll
  for (int k = 0; k < 8; ++k) {
    float ev = expf(sh[t0 + k] - mx);
    e_out[b * L_SEQ + t0 + k] = ev;
    run += ev;
    loc[k] = run;
  }
  ts[tid] = run;
  __syncthreads();
  for (int off = 1; off < 256; off <<= 1) {
    float v = ts[tid];
    float add = (tid >= off) ? ts[tid - off] : 0.f;
    __syncthreads();
    ts[tid] = v + add;
    __syncthreads();
  }
  float prefix = (tid > 0) ? ts[tid - 1] : 0.f;
  #pragma unroll
  for (int k = 0; k < 8; ++k)
    inv_out[b * L_SEQ + t0 + k] = 1.f / (prefix + loc[k]);
}

// ------------- causal Toeplitz conv via MFMA, 256 i-rows per block -------------
__global__ __launch_bounds__(256) void conv_mfma_kernel(
    const unsigned short* __restrict__ vT, const float* __restrict__ e_arr,
    const float* __restrict__ inv_arr, unsigned short* __restrict__ attn_out) {
  __shared__ unsigned short V_s[2][4096];   // 512 chunks of 16B, fragment-major
  __shared__ unsigned short rep[2][8 * 320];
  const int blk = 7 - blockIdx.x;           // heavy blocks first
  const int b = blockIdx.y;
  const int n = b >> 4, h = b & 15;
  const int blkI = blk * 256;
  const int blk4 = blk * 4;
  const int njt = blk4 + 4;
  const int tid = threadIdx.x;
  const int lane = tid & 63;
  const int wave = tid >> 6;
  const int quad = lane >> 4;
  const int mi = lane & 15;
  const float* e_b = e_arr + b * L_SEQ;

  const int c0 = tid, c1 = tid + 256;
  const unsigned short* vsrc0 = vT + (size_t)(b * 64 + (c0 >> 7) * 16 + (c0 & 15)) * L_SEQ + ((c0 >> 4) & 7) * 8;
  const unsigned short* vsrc1 = vT + (size_t)(b * 64 + (c1 >> 7) * 16 + (c1 & 15)) * L_SEQ + ((c1 >> 4) & 7) * 8;

  f32x4 acc[4][4] = {};

  {
    load16_to_lds(vsrc0, &V_s[0][c0 * 8]);
    load16_to_lds(vsrc1, &V_s[0][c1 * 8]);
    const int lagBase = blkI;
    int v = tid;
    int lag = lagBase + 256 - v;
    float ev = (lag >= 0 && lag < L_SEQ) ? e_b[lag] : 0.f;
    unsigned short bfv = f2bf(ev);
    #pragma unroll
    for (int r = 0; r < 8; ++r) { int idx = v - r; if (idx >= 0) rep[0][r * 320 + idx] = bfv; }
    if (tid < 64) {
      v = tid + 256;
      lag = lagBase - tid;
      ev = (lag >= 0 && lag < L_SEQ) ? e_b[lag] : 0.f;
      bfv = f2bf(ev);
      #pragma unroll
      for (int r = 0; r < 8; ++r) rep[0][r * 320 + (v - r)] = bfv;
    }
  }

  for (int jt = 0; jt < njt; ++jt) {
    __syncthreads();
    const int cb = jt & 1;
    if (jt + 1 < njt) {
      const int pb = cb ^ 1;
      const int j0 = (jt + 1) * 64;
      load16_to_lds(vsrc0 + j0, &V_s[pb][c0 * 8]);
      load16_to_lds(vsrc1 + j0, &V_s[pb][c1 * 8]);
      const int lagBase = blkI - j0;
      int v = tid;
      int lag = lagBase + 256 - v;
      float ev = (lag >= 0 && lag < L_SEQ) ? e_b[lag] : 0.f;
      unsigned short bfv = f2bf(ev);
      #pragma unroll
      for (int r = 0; r < 8; ++r) { int idx = v - r; if (idx >= 0) rep[pb][r * 320 + idx] = bfv; }
      if (tid < 64) {
        v = tid + 256;
        lag = lagBase - tid;
        ev = (lag >= 0 && lag < L_SEQ) ? e_b[lag] : 0.f;
        bfv = f2bf(ev);
        #pragma unroll
        for (int r = 0; r < 8; ++r) rep[pb][r * 320 + (v - r)] = bfv;
      }
    }
    if (jt <= blk4 + wave) {
      const unsigned short* Vb = V_s[cb];
      const unsigned short* Rb = rep[cb];
      bf16x8 ef[6];
      #pragma unroll
      for (int q = 0; q < 6; ++q) {
        const int s = 256 - wave * 64 - mi + quad * 8 - 16 * (q - 2);
        const int rr = s & 7;
        ef[q] = *(const bf16x8*)&Rb[rr * 320 + (s - rr)];
      }
      #pragma unroll
      for (int kk = 0; kk < 2; ++kk) {
        bf16x8 bv[4];
        #pragma unroll
        for (int t = 0; t < 4; ++t)
          bv[t] = *(const bf16x8*)&Vb[t * 1024 + kk * 512 + lane * 8];
        #pragma unroll
        for (int isub = 0; isub < 4; ++isub) {
          const int qi = isub - 2 * kk + 2;
          #pragma unroll
          for (int t = 0; t < 4; ++t)
            acc[isub][t] = __builtin_amdgcn_mfma_f32_16x16x32_bf16(ef[qi], bv[t], acc[isub][t], 0, 0, 0);
        }
      }
    }
  }
  #pragma unroll
  for (int isub = 0; isub < 4; ++isub) {
    #pragma unroll
    for (int r = 0; r < 4; ++r) {
      const int i = blkI + wave * 64 + isub * 16 + quad * 4 + r;
      const float iv = inv_arr[b * L_SEQ + i];
      unsigned short* op = &attn_out[((size_t)(n * L_SEQ + i)) * D_EMB + h * 64 + mi];
      #pragma unroll
      for (int t = 0; t < 4; ++t) op[t * 16] = f2bf(acc[isub][t][r] * iv);
    }
  }
}

// ------------- wm[b,j] = (1/L) * sum_{d>=0, j+d<L} e[d]*inv[j+d] -------------
__global__ __launch_bounds__(256) void wmean_kernel(
    const float* __restrict__ e_arr, const float* __restrict__ inv_arr,
    float* __restrict__ out_wm) {
  const int b = blockIdx.x;
  __shared__ float e_s[L_SEQ];
  __shared__ float inv_s[L_SEQ];
  __shared__ float red[256];
  const int tid = threadIdx.x;
  for (int i = tid; i < L_SEQ; i += 256) {
    e_s[i] = e_arr[b * L_SEQ + i];
    inv_s[i] = inv_arr[b * L_SEQ + i];
  }
  __syncthreads();
  const int jj = tid & 127;
  const int h2 = tid >> 7;
  const int j = blockIdx.y * 128 + jj;
  float acc = 0.f;
  for (int d = h2; j + d < L_SEQ; d += 2) acc += e_s[d] * inv_s[j + d];
  red[tid] = acc;
  __syncthreads();
  if (tid < 128)
    out_wm[b * L_SEQ + j] = (red[tid] + red[tid + 128]) * (1.f / (float)L_SEQ);
}

extern "C" void kernel_launch(void* const* d_in, const int* in_sizes, int n_in,
                              void* d_out, int out_size, void* d_ws, size_t ws_size,
                              hipStream_t stream) {
  const float* x       = (const float*)d_in[0];
  const float* W_in    = (const float*)d_in[1];
  const float* b_in    = (const float*)d_in[2];
  const float* Wc      = (const float*)d_in[3];
  const float* bc      = (const float*)d_in[4];
  const float* gamma   = (const float*)d_in[5];
  const float* beta    = (const float*)d_in[6];
  const float* W_out   = (const float*)d_in[7];
  const float* b_out   = (const float*)d_in[8];
  float* out = (float*)d_out;

  const int M = NBATCH * L_SEQ;      // 4096
  // workspace layout (bytes), total ~50.9 MB
  char* ws = (char*)d_ws;
  unsigned short* xa_bf  = (unsigned short*)ws;                 //  8,388,608 (x_bf, later attn_bf)
  unsigned short* Win_bf = (unsigned short*)(ws + 8388608);     //  6,291,456
  unsigned short* Wout_bf= (unsigned short*)(ws + 14680064);    //  2,097,152
  unsigned short* qkv_bf = (unsigned short*)(ws + 16777216);    // 25,165,824 (q,k cols only)
  unsigned short* vT     = (unsigned short*)(ws + 41943040);    //  8,388,608
  float* q_rel = (float*)(ws + 50331648);                       //      8,192
  float* e_arr = (float*)(ws + 50339840);                       //    262,144
  float* inv_a = (float*)(ws + 50601984);                       //    262,144

  hipMemsetAsync(q_rel, 0, BHEADS * HD * sizeof(float), stream);

  // 0) convert x, and both weight matrices, to bf16
  cvt_bf16_kernel<<<dim3(M * D_EMB / 1024), 256, 0, stream>>>(x, xa_bf, M * D_EMB);
  cvt2_bf16_kernel<<<dim3((3 * D_EMB * D_EMB + D_EMB * D_EMB) / 1024), 256, 0, stream>>>(
      W_in, 3 * D_EMB * D_EMB, W_out, D_EMB * D_EMB, Win_bf, Wout_bf);
  // 1) qkv = x @ W_in^T + b_in -> bf16 q,k (row-major) + transposed bf16 vT
  gemm_bt64<true><<<dim3(3 * D_EMB / 128, M / 128), 256, 0, stream>>>(
      xa_bf, Win_bf, b_in, qkv_bf, vT, M, 3 * D_EMB, D_EMB);
  // 2) q_temp -> q_rel sums
  qtemp_qrel_kernel<<<dim3(BHEADS, 16), 256, 0, stream>>>(
      qkv_bf, Wc, bc, gamma, beta, q_rel);
  // 3+4) fused w_row + softmax scan
  wrow_scan_kernel<<<dim3(BHEADS), 256, 0, stream>>>(qkv_bf, q_rel, e_arr, inv_a);
  // 5) causal Toeplitz conv via MFMA -> attn bf16 (into x_bf region)
  conv_mfma_kernel<<<dim3(8, BHEADS), 256, 0, stream>>>(vT, e_arr, inv_a, xa_bf);
  // 6) weights.mean(axis=1) -> second output
  wmean_kernel<<<dim3(BHEADS, L_SEQ / 128), 256, 0, stream>>>(
      e_arr, inv_a, out + (size_t)M * D_EMB);
  // 7) output = attn @ W_out^T + b_out (fp32 out)
  gemm_bt64<false><<<dim3(D_EMB / 128, M / 128), 256, 0, stream>>>(
      xa_bf, Wout_bf, b_out, out, nullptr, M, D_EMB, D_EMB);
}

// Round 6
// 297.239 us; speedup vs baseline: 3.5172x; 1.1270x over previous
//
#include <hip/hip_runtime.h>
#include <math.h>

#define L_SEQ 2048
#define D_EMB 1024
#define NHEADS 16
#define HD 64
#define BHEADS 32   // N*NHEADS
#define NBATCH 2
#define LN_EPS 1e-5f
#define SCALING 0.125f

typedef __attribute__((ext_vector_type(8))) __bf16 bf16x8;
typedef __attribute__((ext_vector_type(4))) float f32x4;
typedef const __attribute__((address_space(1))) unsigned int* gptr_as1;
typedef __attribute__((address_space(3))) unsigned int* lptr_as3;

__device__ __forceinline__ void load16_to_lds(const void* g, void* l) {
  __builtin_amdgcn_global_load_lds((gptr_as1)g, (lptr_as3)l, 16, 0, 0);
}

__device__ __forceinline__ unsigned short f2bf(float f) {
  unsigned int u = __float_as_uint(f);
  u += 0x7fff + ((u >> 16) & 1);   // round-to-nearest-even
  return (unsigned short)(u >> 16);
}

__device__ __forceinline__ float bf2f(unsigned short us) {
  return __uint_as_float((unsigned int)us << 16);
}

// ---------------- fp32 -> bf16 convert (RNE), 4 elems/thread ----------------
__global__ __launch_bounds__(256) void cvt_bf16_kernel(
    const float* __restrict__ in, unsigned short* __restrict__ out, int n) {
  int i = (blockIdx.x * 256 + threadIdx.x) * 4;
  if (i < n) {
    float4 v = *(const float4*)&in[i];
    ushort4 o;
    o.x = f2bf(v.x); o.y = f2bf(v.y); o.z = f2bf(v.z); o.w = f2bf(v.w);
    *(ushort4*)&out[i] = o;
  }
}

// ---------------- three-tensor fp32 -> bf16 convert ----------------
__global__ __launch_bounds__(256) void cvt3_bf16_kernel(
    const float* __restrict__ a, int na, const float* __restrict__ b, int nb,
    const float* __restrict__ c, int nc,
    unsigned short* __restrict__ oa, unsigned short* __restrict__ ob,
    unsigned short* __restrict__ oc) {
  int i = (blockIdx.x * 256 + threadIdx.x) * 4;
  const float* src;
  unsigned short* dst;
  int j;
  if (i < na) { src = a; dst = oa; j = i; }
  else if (i < na + nb) { src = b; dst = ob; j = i - na; }
  else if (i < na + nb + nc) { src = c; dst = oc; j = i - na - nb; }
  else return;
  float4 v = *(const float4*)&src[j];
  ushort4 o;
  o.x = f2bf(v.x); o.y = f2bf(v.y); o.z = f2bf(v.z); o.w = f2bf(v.w);
  *(ushort4*)&dst[j] = o;
}

// ---------------- bf16 MFMA GEMM, BK=32: C = A @ B^T + bias ----------------
// QKV=false: C fp32 row-major (stride Nn).
// QKV=true : cols < 2048 -> bf16 C (stride Nn); cols >= 2048 (v) -> transposed
//            bf16 write into vT[(n*16+h)*64+d][j].
template<bool QKV>
__global__ __launch_bounds__(256) void gemm_bt32(
    const unsigned short* __restrict__ A, const unsigned short* __restrict__ B,
    const float* __restrict__ bias, void* __restrict__ Cout,
    unsigned short* __restrict__ vT, int M, int Nn, int K) {
  __shared__ unsigned short As[4096];   // 128x32 bf16, fragment-major
  __shared__ unsigned short Bs[4096];
  const int bm = blockIdx.y * 128;
  const int bn = blockIdx.x * 128;
  const int tid = threadIdx.x;
  const int lane = tid & 63;
  const int wave = tid >> 6;
  const int wr = (wave >> 1) * 64;
  const int wc = (wave & 1) * 64;

  const int c0 = tid, c1 = tid + 256;
  const unsigned short* ga0 = A + (size_t)(bm + (c0 >> 6) * 16 + (c0 & 15)) * K + ((c0 >> 4) & 3) * 8;
  const unsigned short* ga1 = A + (size_t)(bm + (c1 >> 6) * 16 + (c1 & 15)) * K + ((c1 >> 4) & 3) * 8;
  const unsigned short* gb0 = B + (size_t)(bn + (c0 >> 6) * 16 + (c0 & 15)) * K + ((c0 >> 4) & 3) * 8;
  const unsigned short* gb1 = B + (size_t)(bn + (c1 >> 6) * 16 + (c1 & 15)) * K + ((c1 >> 4) & 3) * 8;

  f32x4 acc[4][4] = {};
  for (int k0 = 0; k0 < K; k0 += 32) {
    load16_to_lds(ga0 + k0, &As[c0 * 8]);
    load16_to_lds(ga1 + k0, &As[c1 * 8]);
    load16_to_lds(gb0 + k0, &Bs[c0 * 8]);
    load16_to_lds(gb1 + k0, &Bs[c1 * 8]);
    __syncthreads();
    bf16x8 af[4], bf[4];
    #pragma unroll
    for (int i = 0; i < 4; ++i)
      af[i] = *(const bf16x8*)&As[((wr >> 4) + i) * 512 + lane * 8];
    #pragma unroll
    for (int j = 0; j < 4; ++j)
      bf[j] = *(const bf16x8*)&Bs[((wc >> 4) + j) * 512 + lane * 8];
    #pragma unroll
    for (int i = 0; i < 4; ++i)
      #pragma unroll
      for (int j = 0; j < 4; ++j)
        acc[i][j] = __builtin_amdgcn_mfma_f32_16x16x32_bf16(af[i], bf[j], acc[i][j], 0, 0, 0);
    __syncthreads();
  }
  const int lc = lane & 15;
  const int lr4 = (lane >> 4) << 2;
  float bv[4];
  #pragma unroll
  for (int j = 0; j < 4; ++j) bv[j] = bias[bn + wc + j * 16 + lc];
  if (!QKV) {
    float* C = (float*)Cout;
    #pragma unroll
    for (int i = 0; i < 4; ++i)
      #pragma unroll
      for (int r = 0; r < 4; ++r) {
        const int row = bm + wr + i * 16 + lr4 + r;
        float* cp = &C[(size_t)row * Nn + bn + wc + lc];
        #pragma unroll
        for (int j = 0; j < 4; ++j) cp[j * 16] = acc[i][j][r] + bv[j];
      }
  } else if (bn < 2 * D_EMB) {
    unsigned short* C = (unsigned short*)Cout;
    #pragma unroll
    for (int i = 0; i < 4; ++i)
      #pragma unroll
      for (int r = 0; r < 4; ++r) {
        const int row = bm + wr + i * 16 + lr4 + r;
        unsigned short* cp = &C[(size_t)row * Nn + bn + wc + lc];
        #pragma unroll
        for (int j = 0; j < 4; ++j) cp[j * 16] = f2bf(acc[i][j][r] + bv[j]);
      }
  } else {
    #pragma unroll
    for (int i = 0; i < 4; ++i) {
      const int row0 = bm + wr + i * 16 + lr4;
      const int n = row0 >> 11;
      const int jseq = row0 & (L_SEQ - 1);
      #pragma unroll
      for (int j = 0; j < 4; ++j) {
        const int col = bn + wc + j * 16 + lc;
        const int d = col & 63;
        const int h = (col >> 6) & 15;
        ushort4 o;
        o.x = f2bf(acc[i][j][0] + bv[j]);
        o.y = f2bf(acc[i][j][1] + bv[j]);
        o.z = f2bf(acc[i][j][2] + bv[j]);
        o.w = f2bf(acc[i][j][3] + bv[j]);
        *(ushort4*)&vT[(size_t)((n * 16 + h) * 64 + d) * L_SEQ + jseq] = o;
      }
    }
  }
}

// ------------- qtemp v2 (MFMA): q_rel_sum[b,o] += sum_l LN(gelu(q @ Wc^T + bc)) -------------
// grid (8 l-chunks, BHEADS), block 256 (4 waves); wave w owns rows l0+w*64..+63.
__global__ __launch_bounds__(256) void qtemp_mfma_kernel(
    const unsigned short* __restrict__ qkv_bf, const unsigned short* __restrict__ Wc_bf,
    const float* __restrict__ bc, const float* __restrict__ gamma,
    const float* __restrict__ beta, float* __restrict__ q_rel_sum) {
  __shared__ unsigned short Qs[16384];  // 256 x 64 bf16, fragment-major (2048 chunks)
  __shared__ unsigned short Ws[4096];   // 64 x 64 bf16, fragment-major (512 chunks)
  __shared__ float red[4][64];
  const int b = blockIdx.y;
  const int n = b >> 4, h = b & 15;
  const int l0 = blockIdx.x * 256;
  const int tid = threadIdx.x;
  const int lane = tid & 63;
  const int wave = tid >> 6;
  const int quad = lane >> 4;
  const int mi = lane & 15;

  // stage Q (8 chunks/thread) and Wc (2 chunks/thread)
  #pragma unroll
  for (int s = 0; s < 8; ++s) {
    const int c = tid + s * 256;
    const int row = ((c >> 7) << 4) + (c & 15);
    const int kof = ((c >> 4) & 7) << 3;
    load16_to_lds(qkv_bf + (size_t)(n * L_SEQ + l0 + row) * (3 * D_EMB) + h * 64 + kof,
                  &Qs[c * 8]);
  }
  #pragma unroll
  for (int s = 0; s < 2; ++s) {
    const int c = tid + s * 256;
    const int row = ((c >> 7) << 4) + (c & 15);
    const int kof = ((c >> 4) & 7) << 3;
    load16_to_lds(Wc_bf + row * 64 + kof, &Ws[c * 8]);
  }
  __syncthreads();

  f32x4 acc[4][4] = {};
  #pragma unroll
  for (int kk = 0; kk < 2; ++kk) {
    const int fo = ((kk * 4 + quad) * 16 + mi) * 8;
    bf16x8 bf[4];
    #pragma unroll
    for (int t = 0; t < 4; ++t) bf[t] = *(const bf16x8*)&Ws[t * 1024 + fo];
    #pragma unroll
    for (int isub = 0; isub < 4; ++isub) {
      const bf16x8 af = *(const bf16x8*)&Qs[(wave * 4 + isub) * 1024 + fo];
      #pragma unroll
      for (int t = 0; t < 4; ++t)
        acc[isub][t] = __builtin_amdgcn_mfma_f32_16x16x32_bf16(af, bf[t], acc[isub][t], 0, 0, 0);
    }
  }

  float bcv[4], gav[4], bev[4], colacc[4];
  #pragma unroll
  for (int t = 0; t < 4; ++t) {
    const int col = t * 16 + mi;
    bcv[t] = bc[col]; gav[t] = gamma[col]; bev[t] = beta[col];
    colacc[t] = 0.f;
  }
  #pragma unroll
  for (int isub = 0; isub < 4; ++isub) {
    #pragma unroll
    for (int r = 0; r < 4; ++r) {
      float g[4];
      float s1 = 0.f, s2 = 0.f;
      #pragma unroll
      for (int t = 0; t < 4; ++t) {
        const float d = acc[isub][t][r] + bcv[t];
        const float gg = 0.5f * d * (1.f + erff(d * 0.70710678118654752f));
        g[t] = gg;
        s1 += gg;
        s2 += gg * gg;
      }
      #pragma unroll
      for (int off = 8; off > 0; off >>= 1) {
        s1 += __shfl_xor(s1, off);
        s2 += __shfl_xor(s2, off);
      }
      const float mu = s1 * (1.f / 64.f);
      const float var = s2 * (1.f / 64.f) - mu * mu;
      const float rs = rsqrtf(var + LN_EPS);
      #pragma unroll
      for (int t = 0; t < 4; ++t)
        colacc[t] += (g[t] - mu) * rs * gav[t] + bev[t];
    }
  }
  // reduce across quads: lanes with same mi hold same cols
  #pragma unroll
  for (int t = 0; t < 4; ++t) {
    colacc[t] += __shfl_xor(colacc[t], 16);
    colacc[t] += __shfl_xor(colacc[t], 32);
  }
  if (quad == 0) {
    #pragma unroll
    for (int t = 0; t < 4; ++t) red[wave][t * 16 + mi] = colacc[t];
  }
  __syncthreads();
  if (wave == 0) {
    float tot = red[0][lane] + red[1][lane] + red[2][lane] + red[3][lane];
    atomicAdd(&q_rel_sum[b * 64 + lane], tot);
  }
}

// ------------- w_row[b,t] = (SCALING/L) * dot(q_rel_sum[b,:], k_head[b,t,:]) -------------
// grid (BHEADS, 8 chunks), 256 threads: one t per thread
__global__ __launch_bounds__(256) void wrow_kernel(
    const unsigned short* __restrict__ qkv_bf, const float* __restrict__ q_rel_sum,
    float* __restrict__ w_row) {
  const int b = blockIdx.x;
  const int n = b >> 4, h = b & 15;
  __shared__ float q_s[64];
  const int tid = threadIdx.x;
  if (tid < 64) q_s[tid] = q_rel_sum[b * 64 + tid] * (SCALING / (float)L_SEQ);
  __syncthreads();
  const int t = blockIdx.y * 256 + tid;
  const unsigned short* kp = &qkv_bf[(size_t)(n * L_SEQ + t) * (3 * D_EMB) + D_EMB + h * 64];
  float acc = 0.f;
  #pragma unroll
  for (int c = 0; c < 64; c += 8) {
    uint4 kv = *(const uint4*)&kp[c];
    acc += q_s[c + 0] * __uint_as_float(kv.x << 16);
    acc += q_s[c + 1] * __uint_as_float(kv.x & 0xffff0000u);
    acc += q_s[c + 2] * __uint_as_float(kv.y << 16);
    acc += q_s[c + 3] * __uint_as_float(kv.y & 0xffff0000u);
    acc += q_s[c + 4] * __uint_as_float(kv.z << 16);
    acc += q_s[c + 5] * __uint_as_float(kv.z & 0xffff0000u);
    acc += q_s[c + 6] * __uint_as_float(kv.w << 16);
    acc += q_s[c + 7] * __uint_as_float(kv.w & 0xffff0000u);
  }
  w_row[b * L_SEQ + t] = acc;
}

// ------------- e[t]=exp(w[t]-max); inv[i]=1/prefix_sum(e) -------------
__global__ __launch_bounds__(256) void scan_kernel(
    const float* __restrict__ w_row, float* __restrict__ e_out,
    float* __restrict__ inv_out) {
  const int b = blockIdx.x;
  const int tid = threadIdx.x;
  __shared__ float sh[L_SEQ];
  __shared__ float ts[256];
  const float* wb = w_row + b * L_SEQ;
  float m = -3.4e38f;
  for (int i = tid; i < L_SEQ; i += 256) {
    float v = wb[i];
    sh[i] = v;
    m = fmaxf(m, v);
  }
  ts[tid] = m;
  __syncthreads();
  for (int off = 128; off > 0; off >>= 1) {
    if (tid < off) ts[tid] = fmaxf(ts[tid], ts[tid + off]);
    __syncthreads();
  }
  const float mx = ts[0];
  __syncthreads();
  const int t0 = tid * 8;
  float loc[8];
  float run = 0.f;
  #pragma unroll
  for (int k = 0; k < 8; ++k) {
    float ev = expf(sh[t0 + k] - mx);
    e_out[b * L_SEQ + t0 + k] = ev;
    run += ev;
    loc[k] = run;
  }
  ts[tid] = run;
  __syncthreads();
  for (int off = 1; off < 256; off <<= 1) {
    float v = ts[tid];
    float add = (tid >= off) ? ts[tid - off] : 0.f;
    __syncthreads();
    ts[tid] = v + add;
    __syncthreads();
  }
  float prefix = (tid > 0) ? ts[tid - 1] : 0.f;
  #pragma unroll
  for (int k = 0; k < 8; ++k)
    inv_out[b * L_SEQ + t0 + k] = 1.f / (prefix + loc[k]);
}

// ------------- causal Toeplitz conv via MFMA, 256 i-rows per block -------------
__global__ __launch_bounds__(256) void conv_mfma_kernel(
    const unsigned short* __restrict__ vT, const float* __restrict__ e_arr,
    const float* __restrict__ inv_arr, unsigned short* __restrict__ attn_out) {
  __shared__ unsigned short V_s[2][4096];
  __shared__ unsigned short rep[2][8 * 320];
  const int blk = 7 - blockIdx.x;           // heavy blocks first
  const int b = blockIdx.y;
  const int n = b >> 4, h = b & 15;
  const int blkI = blk * 256;
  const int blk4 = blk * 4;
  const int njt = blk4 + 4;
  const int tid = threadIdx.x;
  const int lane = tid & 63;
  const int wave = tid >> 6;
  const int quad = lane >> 4;
  const int mi = lane & 15;
  const float* e_b = e_arr + b * L_SEQ;

  const int c0 = tid, c1 = tid + 256;
  const unsigned short* vsrc0 = vT + (size_t)(b * 64 + (c0 >> 7) * 16 + (c0 & 15)) * L_SEQ + ((c0 >> 4) & 7) * 8;
  const unsigned short* vsrc1 = vT + (size_t)(b * 64 + (c1 >> 7) * 16 + (c1 & 15)) * L_SEQ + ((c1 >> 4) & 7) * 8;

  f32x4 acc[4][4] = {};

  {
    load16_to_lds(vsrc0, &V_s[0][c0 * 8]);
    load16_to_lds(vsrc1, &V_s[0][c1 * 8]);
    const int lagBase = blkI;
    int v = tid;
    int lag = lagBase + 256 - v;
    float ev = (lag >= 0 && lag < L_SEQ) ? e_b[lag] : 0.f;
    unsigned short bfv = f2bf(ev);
    #pragma unroll
    for (int r = 0; r < 8; ++r) { int idx = v - r; if (idx >= 0) rep[0][r * 320 + idx] = bfv; }
    if (tid < 64) {
      v = tid + 256;
      lag = lagBase - tid;
      ev = (lag >= 0 && lag < L_SEQ) ? e_b[lag] : 0.f;
      bfv = f2bf(ev);
      #pragma unroll
      for (int r = 0; r < 8; ++r) rep[0][r * 320 + (v - r)] = bfv;
    }
  }

  for (int jt = 0; jt < njt; ++jt) {
    __syncthreads();
    const int cb = jt & 1;
    if (jt + 1 < njt) {
      const int pb = cb ^ 1;
      const int j0 = (jt + 1) * 64;
      load16_to_lds(vsrc0 + j0, &V_s[pb][c0 * 8]);
      load16_to_lds(vsrc1 + j0, &V_s[pb][c1 * 8]);
      const int lagBase = blkI - j0;
      int v = tid;
      int lag = lagBase + 256 - v;
      float ev = (lag >= 0 && lag < L_SEQ) ? e_b[lag] : 0.f;
      unsigned short bfv = f2bf(ev);
      #pragma unroll
      for (int r = 0; r < 8; ++r) { int idx = v - r; if (idx >= 0) rep[pb][r * 320 + idx] = bfv; }
      if (tid < 64) {
        v = tid + 256;
        lag = lagBase - tid;
        ev = (lag >= 0 && lag < L_SEQ) ? e_b[lag] : 0.f;
        bfv = f2bf(ev);
        #pragma unroll
        for (int r = 0; r < 8; ++r) rep[pb][r * 320 + (v - r)] = bfv;
      }
    }
    if (jt <= blk4 + wave) {
      const unsigned short* Vb = V_s[cb];
      const unsigned short* Rb = rep[cb];
      bf16x8 ef[6];
      #pragma unroll
      for (int q = 0; q < 6; ++q) {
        const int s = 256 - wave * 64 - mi + quad * 8 - 16 * (q - 2);
        const int rr = s & 7;
        ef[q] = *(const bf16x8*)&Rb[rr * 320 + (s - rr)];
      }
      #pragma unroll
      for (int kk = 0; kk < 2; ++kk) {
        bf16x8 bv[4];
        #pragma unroll
        for (int t = 0; t < 4; ++t)
          bv[t] = *(const bf16x8*)&Vb[t * 1024 + kk * 512 + lane * 8];
        #pragma unroll
        for (int isub = 0; isub < 4; ++isub) {
          const int qi = isub - 2 * kk + 2;
          #pragma unroll
          for (int t = 0; t < 4; ++t)
            acc[isub][t] = __builtin_amdgcn_mfma_f32_16x16x32_bf16(ef[qi], bv[t], acc[isub][t], 0, 0, 0);
        }
      }
    }
  }
  #pragma unroll
  for (int isub = 0; isub < 4; ++isub) {
    #pragma unroll
    for (int r = 0; r < 4; ++r) {
      const int i = blkI + wave * 64 + isub * 16 + quad * 4 + r;
      const float iv = inv_arr[b * L_SEQ + i];
      unsigned short* op = &attn_out[((size_t)(n * L_SEQ + i)) * D_EMB + h * 64 + mi];
      #pragma unroll
      for (int t = 0; t < 4; ++t) op[t * 16] = f2bf(acc[isub][t][r] * iv);
    }
  }
}

// ------------- wm[b,j] = (1/L) * sum_{d>=0, j+d<L} e[d]*inv[j+d] -------------
__global__ __launch_bounds__(256) void wmean_kernel(
    const float* __restrict__ e_arr, const float* __restrict__ inv_arr,
    float* __restrict__ out_wm) {
  const int b = blockIdx.x;
  __shared__ float e_s[L_SEQ];
  __shared__ float inv_s[L_SEQ];
  __shared__ float red[256];
  const int tid = threadIdx.x;
  for (int i = tid; i < L_SEQ; i += 256) {
    e_s[i] = e_arr[b * L_SEQ + i];
    inv_s[i] = inv_arr[b * L_SEQ + i];
  }
  __syncthreads();
  const int jj = tid & 127;
  const int h2 = tid >> 7;
  const int j = blockIdx.y * 128 + jj;
  float acc = 0.f;
  for (int d = h2; j + d < L_SEQ; d += 2) acc += e_s[d] * inv_s[j + d];
  red[tid] = acc;
  __syncthreads();
  if (tid < 128)
    out_wm[b * L_SEQ + j] = (red[tid] + red[tid + 128]) * (1.f / (float)L_SEQ);
}

extern "C" void kernel_launch(void* const* d_in, const int* in_sizes, int n_in,
                              void* d_out, int out_size, void* d_ws, size_t ws_size,
                              hipStream_t stream) {
  const float* x       = (const float*)d_in[0];
  const float* W_in    = (const float*)d_in[1];
  const float* b_in    = (const float*)d_in[2];
  const float* Wc      = (const float*)d_in[3];
  const float* bc      = (const float*)d_in[4];
  const float* gamma   = (const float*)d_in[5];
  const float* beta    = (const float*)d_in[6];
  const float* W_out   = (const float*)d_in[7];
  const float* b_out   = (const float*)d_in[8];
  float* out = (float*)d_out;

  const int M = NBATCH * L_SEQ;      // 4096
  // workspace layout (bytes), total ~51.2 MB
  char* ws = (char*)d_ws;
  unsigned short* xa_bf  = (unsigned short*)ws;                 //  8,388,608 (x_bf, later attn_bf)
  unsigned short* Win_bf = (unsigned short*)(ws + 8388608);     //  6,291,456
  unsigned short* Wout_bf= (unsigned short*)(ws + 14680064);    //  2,097,152
  unsigned short* qkv_bf = (unsigned short*)(ws + 16777216);    // 25,165,824 (q,k cols only)
  unsigned short* vT     = (unsigned short*)(ws + 41943040);    //  8,388,608
  float* q_rel = (float*)(ws + 50331648);                       //      8,192
  float* e_arr = (float*)(ws + 50339840);                       //    262,144
  float* inv_a = (float*)(ws + 50601984);                       //    262,144
  float* w_row = (float*)(ws + 50864128);                       //    262,144
  unsigned short* Wc_bf  = (unsigned short*)(ws + 51126272);    //      8,192

  hipMemsetAsync(q_rel, 0, BHEADS * HD * sizeof(float), stream);

  // 0) convert x; W_in + W_out + Wc
  cvt_bf16_kernel<<<dim3(M * D_EMB / 1024), 256, 0, stream>>>(x, xa_bf, M * D_EMB);
  cvt3_bf16_kernel<<<dim3((3 * D_EMB * D_EMB + D_EMB * D_EMB + HD * HD) / 1024), 256, 0, stream>>>(
      W_in, 3 * D_EMB * D_EMB, W_out, D_EMB * D_EMB, Wc, HD * HD, Win_bf, Wout_bf, Wc_bf);
  // 1) qkv = x @ W_in^T + b_in -> bf16 q,k (row-major) + transposed bf16 vT
  gemm_bt32<true><<<dim3(3 * D_EMB / 128, M / 128), 256, 0, stream>>>(
      xa_bf, Win_bf, b_in, qkv_bf, vT, M, 3 * D_EMB, D_EMB);
  // 2) q_temp -> q_rel sums (MFMA)
  qtemp_mfma_kernel<<<dim3(8, BHEADS), 256, 0, stream>>>(
      qkv_bf, Wc_bf, bc, gamma, beta, q_rel);
  // 3) w_row gemv (wide)
  wrow_kernel<<<dim3(BHEADS, 8), 256, 0, stream>>>(qkv_bf, q_rel, w_row);
  // 4) softmax scan
  scan_kernel<<<dim3(BHEADS), 256, 0, stream>>>(w_row, e_arr, inv_a);
  // 5) causal Toeplitz conv via MFMA -> attn bf16 (into x_bf region)
  conv_mfma_kernel<<<dim3(8, BHEADS), 256, 0, stream>>>(vT, e_arr, inv_a, xa_bf);
  // 6) weights.mean(axis=1) -> second output
  wmean_kernel<<<dim3(BHEADS, L_SEQ / 128), 256, 0, stream>>>(
      e_arr, inv_a, out + (size_t)M * D_EMB);
  // 7) output = attn @ W_out^T + b_out (fp32 out)
  gemm_bt32<false><<<dim3(D_EMB / 128, M / 128), 256, 0, stream>>>(
      xa_bf, Wout_bf, b_out, out, nullptr, M, D_EMB, D_EMB);
}

// Round 7
// 277.425 us; speedup vs baseline: 3.7684x; 1.0714x over previous
//
#include <hip/hip_runtime.h>
#include <math.h>

#define L_SEQ 2048
#define D_EMB 1024
#define NHEADS 16
#define HD 64
#define BHEADS 32   // N*NHEADS
#define NBATCH 2
#define LN_EPS 1e-5f
#define SCALING 0.125f

typedef __attribute__((ext_vector_type(8))) __bf16 bf16x8;
typedef __attribute__((ext_vector_type(4))) float f32x4;
typedef const __attribute__((address_space(1))) unsigned int* gptr_as1;
typedef __attribute__((address_space(3))) unsigned int* lptr_as3;

__device__ __forceinline__ void load16_to_lds(const void* g, void* l) {
  __builtin_amdgcn_global_load_lds((gptr_as1)g, (lptr_as3)l, 16, 0, 0);
}

__device__ __forceinline__ unsigned short f2bf(float f) {
  unsigned int u = __float_as_uint(f);
  u += 0x7fff + ((u >> 16) & 1);   // round-to-nearest-even
  return (unsigned short)(u >> 16);
}

// ---------------- four-tensor fp32 -> bf16 convert ----------------
__global__ __launch_bounds__(256) void cvt4_bf16_kernel(
    const float* __restrict__ a, int na, const float* __restrict__ b, int nb,
    const float* __restrict__ c, int nc, const float* __restrict__ d, int nd,
    unsigned short* __restrict__ oa, unsigned short* __restrict__ ob,
    unsigned short* __restrict__ oc, unsigned short* __restrict__ od) {
  int i = (blockIdx.x * 256 + threadIdx.x) * 4;
  const float* src;
  unsigned short* dst;
  int j;
  if (i < na) { src = a; dst = oa; j = i; }
  else if (i < na + nb) { src = b; dst = ob; j = i - na; }
  else if (i < na + nb + nc) { src = c; dst = oc; j = i - na - nb; }
  else if (i < na + nb + nc + nd) { src = d; dst = od; j = i - na - nb - nc; }
  else return;
  float4 v = *(const float4*)&src[j];
  ushort4 o;
  o.x = f2bf(v.x); o.y = f2bf(v.y); o.z = f2bf(v.z); o.w = f2bf(v.w);
  *(ushort4*)&dst[j] = o;
}

// ---------------- qkv GEMM, 128x128, BK=32: bf16 q,k + transposed vT ----------------
__global__ __launch_bounds__(256) void gemm_qkv(
    const unsigned short* __restrict__ A, const unsigned short* __restrict__ B,
    const float* __restrict__ bias, unsigned short* __restrict__ Cbf,
    unsigned short* __restrict__ vT, int M, int Nn, int K) {
  __shared__ unsigned short As[4096];   // 128x32 bf16, fragment-major
  __shared__ unsigned short Bs[4096];
  // by-pair swizzle: pairs of row-tiles iterate col-tiles together (B L2 reuse)
  const int id = blockIdx.y * 24 + blockIdx.x;
  const int by = (id / 48) * 2 + (id & 1);
  const int bx = (id % 48) >> 1;
  const int bm = by * 128;
  const int bn = bx * 128;
  const int tid = threadIdx.x;
  const int lane = tid & 63;
  const int wave = tid >> 6;
  const int wr = (wave >> 1) * 64;
  const int wc = (wave & 1) * 64;

  const int c0 = tid, c1 = tid + 256;
  const unsigned short* ga0 = A + (size_t)(bm + (c0 >> 6) * 16 + (c0 & 15)) * K + ((c0 >> 4) & 3) * 8;
  const unsigned short* ga1 = A + (size_t)(bm + (c1 >> 6) * 16 + (c1 & 15)) * K + ((c1 >> 4) & 3) * 8;
  const unsigned short* gb0 = B + (size_t)(bn + (c0 >> 6) * 16 + (c0 & 15)) * K + ((c0 >> 4) & 3) * 8;
  const unsigned short* gb1 = B + (size_t)(bn + (c1 >> 6) * 16 + (c1 & 15)) * K + ((c1 >> 4) & 3) * 8;

  f32x4 acc[4][4] = {};
  for (int k0 = 0; k0 < K; k0 += 32) {
    load16_to_lds(ga0 + k0, &As[c0 * 8]);
    load16_to_lds(ga1 + k0, &As[c1 * 8]);
    load16_to_lds(gb0 + k0, &Bs[c0 * 8]);
    load16_to_lds(gb1 + k0, &Bs[c1 * 8]);
    __syncthreads();
    bf16x8 af[4], bf[4];
    #pragma unroll
    for (int i = 0; i < 4; ++i)
      af[i] = *(const bf16x8*)&As[((wr >> 4) + i) * 512 + lane * 8];
    #pragma unroll
    for (int j = 0; j < 4; ++j)
      bf[j] = *(const bf16x8*)&Bs[((wc >> 4) + j) * 512 + lane * 8];
    #pragma unroll
    for (int i = 0; i < 4; ++i)
      #pragma unroll
      for (int j = 0; j < 4; ++j)
        acc[i][j] = __builtin_amdgcn_mfma_f32_16x16x32_bf16(af[i], bf[j], acc[i][j], 0, 0, 0);
    __syncthreads();
  }
  const int lc = lane & 15;
  const int lr4 = (lane >> 4) << 2;
  float bv[4];
  #pragma unroll
  for (int j = 0; j < 4; ++j) bv[j] = bias[bn + wc + j * 16 + lc];
  if (bn < 2 * D_EMB) {
    #pragma unroll
    for (int i = 0; i < 4; ++i)
      #pragma unroll
      for (int r = 0; r < 4; ++r) {
        const int row = bm + wr + i * 16 + lr4 + r;
        unsigned short* cp = &Cbf[(size_t)row * Nn + bn + wc + lc];
        #pragma unroll
        for (int j = 0; j < 4; ++j) cp[j * 16] = f2bf(acc[i][j][r] + bv[j]);
      }
  } else {
    #pragma unroll
    for (int i = 0; i < 4; ++i) {
      const int row0 = bm + wr + i * 16 + lr4;
      const int n = row0 >> 11;
      const int jseq = row0 & (L_SEQ - 1);
      #pragma unroll
      for (int j = 0; j < 4; ++j) {
        const int col = bn + wc + j * 16 + lc;
        const int d = col & 63;
        const int h = (col >> 6) & 15;
        ushort4 o;
        o.x = f2bf(acc[i][j][0] + bv[j]);
        o.y = f2bf(acc[i][j][1] + bv[j]);
        o.z = f2bf(acc[i][j][2] + bv[j]);
        o.w = f2bf(acc[i][j][3] + bv[j]);
        *(ushort4*)&vT[(size_t)((n * 16 + h) * 64 + d) * L_SEQ + jseq] = o;
      }
    }
  }
}

// ---------------- out GEMM, 64x128 tile (512 blocks = 2/CU), fp32 out ----------------
__global__ __launch_bounds__(256) void gemm_out64(
    const unsigned short* __restrict__ A, const unsigned short* __restrict__ B,
    const float* __restrict__ bias, float* __restrict__ C,
    int M, int Nn, int K) {
  __shared__ unsigned short As[2048];   // 64x32
  __shared__ unsigned short Bs[4096];   // 128x32
  const int bm = blockIdx.y * 64;
  const int bn = blockIdx.x * 128;
  const int tid = threadIdx.x;
  const int lane = tid & 63;
  const int wave = tid >> 6;
  const int wr = (wave >> 1) * 32;
  const int wc = (wave & 1) * 64;

  const int ca = tid;                   // A: 1 chunk/thread
  const int cb0 = tid, cb1 = tid + 256; // B: 2 chunks/thread
  const unsigned short* ga = A + (size_t)(bm + (ca >> 6) * 16 + (ca & 15)) * K + ((ca >> 4) & 3) * 8;
  const unsigned short* gb0 = B + (size_t)(bn + (cb0 >> 6) * 16 + (cb0 & 15)) * K + ((cb0 >> 4) & 3) * 8;
  const unsigned short* gb1 = B + (size_t)(bn + (cb1 >> 6) * 16 + (cb1 & 15)) * K + ((cb1 >> 4) & 3) * 8;

  f32x4 acc[2][4] = {};
  for (int k0 = 0; k0 < K; k0 += 32) {
    load16_to_lds(ga + k0, &As[ca * 8]);
    load16_to_lds(gb0 + k0, &Bs[cb0 * 8]);
    load16_to_lds(gb1 + k0, &Bs[cb1 * 8]);
    __syncthreads();
    bf16x8 af[2], bf[4];
    #pragma unroll
    for (int i = 0; i < 2; ++i)
      af[i] = *(const bf16x8*)&As[((wr >> 4) + i) * 512 + lane * 8];
    #pragma unroll
    for (int j = 0; j < 4; ++j)
      bf[j] = *(const bf16x8*)&Bs[((wc >> 4) + j) * 512 + lane * 8];
    #pragma unroll
    for (int i = 0; i < 2; ++i)
      #pragma unroll
      for (int j = 0; j < 4; ++j)
        acc[i][j] = __builtin_amdgcn_mfma_f32_16x16x32_bf16(af[i], bf[j], acc[i][j], 0, 0, 0);
    __syncthreads();
  }
  const int lc = lane & 15;
  const int lr4 = (lane >> 4) << 2;
  float bv[4];
  #pragma unroll
  for (int j = 0; j < 4; ++j) bv[j] = bias[bn + wc + j * 16 + lc];
  #pragma unroll
  for (int i = 0; i < 2; ++i)
    #pragma unroll
    for (int r = 0; r < 4; ++r) {
      const int row = bm + wr + i * 16 + lr4 + r;
      float* cp = &C[(size_t)row * Nn + bn + wc + lc];
      #pragma unroll
      for (int j = 0; j < 4; ++j) cp[j * 16] = acc[i][j][r] + bv[j];
    }
}

// ------------- qtemp (MFMA), 128-row chunks (512 blocks = 2/CU) -------------
__global__ __launch_bounds__(256) void qtemp_mfma_kernel(
    const unsigned short* __restrict__ qkv_bf, const unsigned short* __restrict__ Wc_bf,
    const float* __restrict__ bc, const float* __restrict__ gamma,
    const float* __restrict__ beta, float* __restrict__ q_rel_sum) {
  __shared__ unsigned short Qs[8192];   // 128 x 64 bf16, fragment-major
  __shared__ unsigned short Ws[4096];   // 64 x 64
  __shared__ float red[4][64];
  const int b = blockIdx.y;
  const int n = b >> 4, h = b & 15;
  const int l0 = blockIdx.x * 128;
  const int tid = threadIdx.x;
  const int lane = tid & 63;
  const int wave = tid >> 6;
  const int quad = lane >> 4;
  const int mi = lane & 15;

  #pragma unroll
  for (int s = 0; s < 4; ++s) {
    const int c = tid + s * 256;
    const int row = ((c >> 7) << 4) + (c & 15);
    const int kof = ((c >> 4) & 7) << 3;
    load16_to_lds(qkv_bf + (size_t)(n * L_SEQ + l0 + row) * (3 * D_EMB) + h * 64 + kof,
                  &Qs[c * 8]);
  }
  #pragma unroll
  for (int s = 0; s < 2; ++s) {
    const int c = tid + s * 256;
    const int row = ((c >> 7) << 4) + (c & 15);
    const int kof = ((c >> 4) & 7) << 3;
    load16_to_lds(Wc_bf + row * 64 + kof, &Ws[c * 8]);
  }
  __syncthreads();

  f32x4 acc[2][4] = {};
  #pragma unroll
  for (int kk = 0; kk < 2; ++kk) {
    const int fo = ((kk * 4 + quad) * 16 + mi) * 8;
    bf16x8 bf[4];
    #pragma unroll
    for (int t = 0; t < 4; ++t) bf[t] = *(const bf16x8*)&Ws[t * 1024 + fo];
    #pragma unroll
    for (int isub = 0; isub < 2; ++isub) {
      const bf16x8 af = *(const bf16x8*)&Qs[(wave * 2 + isub) * 1024 + fo];
      #pragma unroll
      for (int t = 0; t < 4; ++t)
        acc[isub][t] = __builtin_amdgcn_mfma_f32_16x16x32_bf16(af, bf[t], acc[isub][t], 0, 0, 0);
    }
  }

  float bcv[4], gav[4], bev[4], colacc[4];
  #pragma unroll
  for (int t = 0; t < 4; ++t) {
    const int col = t * 16 + mi;
    bcv[t] = bc[col]; gav[t] = gamma[col]; bev[t] = beta[col];
    colacc[t] = 0.f;
  }
  #pragma unroll
  for (int isub = 0; isub < 2; ++isub) {
    #pragma unroll
    for (int r = 0; r < 4; ++r) {
      float g[4];
      float s1 = 0.f, s2 = 0.f;
      #pragma unroll
      for (int t = 0; t < 4; ++t) {
        const float d = acc[isub][t][r] + bcv[t];
        const float gg = 0.5f * d * (1.f + erff(d * 0.70710678118654752f));
        g[t] = gg;
        s1 += gg;
        s2 += gg * gg;
      }
      #pragma unroll
      for (int off = 8; off > 0; off >>= 1) {
        s1 += __shfl_xor(s1, off);
        s2 += __shfl_xor(s2, off);
      }
      const float mu = s1 * (1.f / 64.f);
      const float var = s2 * (1.f / 64.f) - mu * mu;
      const float rs = rsqrtf(var + LN_EPS);
      #pragma unroll
      for (int t = 0; t < 4; ++t)
        colacc[t] += (g[t] - mu) * rs * gav[t] + bev[t];
    }
  }
  #pragma unroll
  for (int t = 0; t < 4; ++t) {
    colacc[t] += __shfl_xor(colacc[t], 16);
    colacc[t] += __shfl_xor(colacc[t], 32);
  }
  if (quad == 0) {
    #pragma unroll
    for (int t = 0; t < 4; ++t) red[wave][t * 16 + mi] = colacc[t];
  }
  __syncthreads();
  if (wave == 0) {
    float tot = red[0][lane] + red[1][lane] + red[2][lane] + red[3][lane];
    atomicAdd(&q_rel_sum[b * 64 + lane], tot);
  }
}

// ------------- w_row[b,t] = (SCALING/L) * dot(q_rel_sum[b,:], k_head[b,t,:]) -------------
__global__ __launch_bounds__(256) void wrow_kernel(
    const unsigned short* __restrict__ qkv_bf, const float* __restrict__ q_rel_sum,
    float* __restrict__ w_row) {
  const int b = blockIdx.x;
  const int n = b >> 4, h = b & 15;
  __shared__ float q_s[64];
  const int tid = threadIdx.x;
  if (tid < 64) q_s[tid] = q_rel_sum[b * 64 + tid] * (SCALING / (float)L_SEQ);
  __syncthreads();
  const int t = blockIdx.y * 256 + tid;
  const unsigned short* kp = &qkv_bf[(size_t)(n * L_SEQ + t) * (3 * D_EMB) + D_EMB + h * 64];
  float acc = 0.f;
  #pragma unroll
  for (int c = 0; c < 64; c += 8) {
    uint4 kv = *(const uint4*)&kp[c];
    acc += q_s[c + 0] * __uint_as_float(kv.x << 16);
    acc += q_s[c + 1] * __uint_as_float(kv.x & 0xffff0000u);
    acc += q_s[c + 2] * __uint_as_float(kv.y << 16);
    acc += q_s[c + 3] * __uint_as_float(kv.y & 0xffff0000u);
    acc += q_s[c + 4] * __uint_as_float(kv.z << 16);
    acc += q_s[c + 5] * __uint_as_float(kv.z & 0xffff0000u);
    acc += q_s[c + 6] * __uint_as_float(kv.w << 16);
    acc += q_s[c + 7] * __uint_as_float(kv.w & 0xffff0000u);
  }
  w_row[b * L_SEQ + t] = acc;
}

// ------------- e[t]=exp(w[t]-max); inv[i]=1/prefix_sum(e) -------------
__global__ __launch_bounds__(256) void scan_kernel(
    const float* __restrict__ w_row, float* __restrict__ e_out,
    float* __restrict__ inv_out) {
  const int b = blockIdx.x;
  const int tid = threadIdx.x;
  __shared__ float sh[L_SEQ];
  __shared__ float ts[256];
  const float* wb = w_row + b * L_SEQ;
  float m = -3.4e38f;
  for (int i = tid; i < L_SEQ; i += 256) {
    float v = wb[i];
    sh[i] = v;
    m = fmaxf(m, v);
  }
  ts[tid] = m;
  __syncthreads();
  for (int off = 128; off > 0; off >>= 1) {
    if (tid < off) ts[tid] = fmaxf(ts[tid], ts[tid + off]);
    __syncthreads();
  }
  const float mx = ts[0];
  __syncthreads();
  const int t0 = tid * 8;
  float loc[8];
  float run = 0.f;
  #pragma unroll
  for (int k = 0; k < 8; ++k) {
    float ev = expf(sh[t0 + k] - mx);
    e_out[b * L_SEQ + t0 + k] = ev;
    run += ev;
    loc[k] = run;
  }
  ts[tid] = run;
  __syncthreads();
  for (int off = 1; off < 256; off <<= 1) {
    float v = ts[tid];
    float add = (tid >= off) ? ts[tid - off] : 0.f;
    __syncthreads();
    ts[tid] = v + add;
    __syncthreads();
  }
  float prefix = (tid > 0) ? ts[tid - 1] : 0.f;
  #pragma unroll
  for (int k = 0; k < 8; ++k)
    inv_out[b * L_SEQ + t0 + k] = 1.f / (prefix + loc[k]);
}

// ------------- causal Toeplitz conv via MFMA, d-split x2 (512 blocks = 2/CU) -------------
__global__ __launch_bounds__(256) void conv_mfma_kernel(
    const unsigned short* __restrict__ vT, const float* __restrict__ e_arr,
    const float* __restrict__ inv_arr, unsigned short* __restrict__ attn_out) {
  __shared__ unsigned short V_s[2][2048];   // 256 chunks of 16B (32 d x 64 j)
  __shared__ unsigned short rep[2][8 * 320];
  const int blk = 7 - blockIdx.x;           // heavy blocks first
  const int b = blockIdx.y;
  const int dh = blockIdx.z;                // d-half: 0 or 1
  const int n = b >> 4, h = b & 15;
  const int blkI = blk * 256;
  const int blk4 = blk * 4;
  const int njt = blk4 + 4;
  const int tid = threadIdx.x;
  const int lane = tid & 63;
  const int wave = tid >> 6;
  const int quad = lane >> 4;
  const int mi = lane & 15;
  const float* e_b = e_arr + b * L_SEQ;

  // staging: 1 chunk/thread: d_local = (c>>7)*16+(c&15), q = (c>>4)&7
  const unsigned short* vsrc = vT +
      (size_t)(b * 64 + dh * 32 + (tid >> 7) * 16 + (tid & 15)) * L_SEQ + ((tid >> 4) & 7) * 8;

  f32x4 acc[4][2] = {};

  {
    load16_to_lds(vsrc, &V_s[0][tid * 8]);
    const int lagBase = blkI;
    int v = tid;
    int lag = lagBase + 256 - v;
    float ev = (lag >= 0 && lag < L_SEQ) ? e_b[lag] : 0.f;
    unsigned short bfv = f2bf(ev);
    #pragma unroll
    for (int r = 0; r < 8; ++r) { int idx = v - r; if (idx >= 0) rep[0][r * 320 + idx] = bfv; }
    if (tid < 64) {
      v = tid + 256;
      lag = lagBase - tid;
      ev = (lag >= 0 && lag < L_SEQ) ? e_b[lag] : 0.f;
      bfv = f2bf(ev);
      #pragma unroll
      for (int r = 0; r < 8; ++r) rep[0][r * 320 + (v - r)] = bfv;
    }
  }

  for (int jt = 0; jt < njt; ++jt) {
    __syncthreads();
    const int cb = jt & 1;
    if (jt + 1 < njt) {
      const int pb = cb ^ 1;
      const int j0 = (jt + 1) * 64;
      load16_to_lds(vsrc + j0, &V_s[pb][tid * 8]);
      const int lagBase = blkI - j0;
      int v = tid;
      int lag = lagBase + 256 - v;
      float ev = (lag >= 0 && lag < L_SEQ) ? e_b[lag] : 0.f;
      unsigned short bfv = f2bf(ev);
      #pragma unroll
      for (int r = 0; r < 8; ++r) { int idx = v - r; if (idx >= 0) rep[pb][r * 320 + idx] = bfv; }
      if (tid < 64) {
        v = tid + 256;
        lag = lagBase - tid;
        ev = (lag >= 0 && lag < L_SEQ) ? e_b[lag] : 0.f;
        bfv = f2bf(ev);
        #pragma unroll
        for (int r = 0; r < 8; ++r) rep[pb][r * 320 + (v - r)] = bfv;
      }
    }
    if (jt <= blk4 + wave) {
      const unsigned short* Vb = V_s[cb];
      const unsigned short* Rb = rep[cb];
      bf16x8 ef[6];
      #pragma unroll
      for (int q = 0; q < 6; ++q) {
        const int s = 256 - wave * 64 - mi + quad * 8 - 16 * (q - 2);
        const int rr = s & 7;
        ef[q] = *(const bf16x8*)&Rb[rr * 320 + (s - rr)];
      }
      #pragma unroll
      for (int kk = 0; kk < 2; ++kk) {
        bf16x8 bv[2];
        #pragma unroll
        for (int t = 0; t < 2; ++t)
          bv[t] = *(const bf16x8*)&Vb[t * 1024 + kk * 512 + lane * 8];
        #pragma unroll
        for (int isub = 0; isub < 4; ++isub) {
          const int qi = isub - 2 * kk + 2;
          #pragma unroll
          for (int t = 0; t < 2; ++t)
            acc[isub][t] = __builtin_amdgcn_mfma_f32_16x16x32_bf16(ef[qi], bv[t], acc[isub][t], 0, 0, 0);
        }
      }
    }
  }
  #pragma unroll
  for (int isub = 0; isub < 4; ++isub) {
    #pragma unroll
    for (int r = 0; r < 4; ++r) {
      const int i = blkI + wave * 64 + isub * 16 + quad * 4 + r;
      const float iv = inv_arr[b * L_SEQ + i];
      unsigned short* op = &attn_out[((size_t)(n * L_SEQ + i)) * D_EMB + h * 64 + dh * 32 + mi];
      #pragma unroll
      for (int t = 0; t < 2; ++t) op[t * 16] = f2bf(acc[isub][t][r] * iv);
    }
  }
}

// ------------- wm[b,j] = (1/L) * sum_{d>=0, j+d<L} e[d]*inv[j+d] -------------
__global__ __launch_bounds__(256) void wmean_kernel(
    const float* __restrict__ e_arr, const float* __restrict__ inv_arr,
    float* __restrict__ out_wm) {
  const int b = blockIdx.x;
  __shared__ float e_s[L_SEQ];
  __shared__ float inv_s[L_SEQ];
  __shared__ float red[256];
  const int tid = threadIdx.x;
  for (int i = tid; i < L_SEQ; i += 256) {
    e_s[i] = e_arr[b * L_SEQ + i];
    inv_s[i] = inv_arr[b * L_SEQ + i];
  }
  __syncthreads();
  const int jj = tid & 127;
  const int h2 = tid >> 7;
  const int j = blockIdx.y * 128 + jj;
  float acc = 0.f;
  for (int d = h2; j + d < L_SEQ; d += 2) acc += e_s[d] * inv_s[j + d];
  red[tid] = acc;
  __syncthreads();
  if (tid < 128)
    out_wm[b * L_SEQ + j] = (red[tid] + red[tid + 128]) * (1.f / (float)L_SEQ);
}

extern "C" void kernel_launch(void* const* d_in, const int* in_sizes, int n_in,
                              void* d_out, int out_size, void* d_ws, size_t ws_size,
                              hipStream_t stream) {
  const float* x       = (const float*)d_in[0];
  const float* W_in    = (const float*)d_in[1];
  const float* b_in    = (const float*)d_in[2];
  const float* Wc      = (const float*)d_in[3];
  const float* bc      = (const float*)d_in[4];
  const float* gamma   = (const float*)d_in[5];
  const float* beta    = (const float*)d_in[6];
  const float* W_out   = (const float*)d_in[7];
  const float* b_out   = (const float*)d_in[8];
  float* out = (float*)d_out;

  const int M = NBATCH * L_SEQ;      // 4096
  char* ws = (char*)d_ws;
  unsigned short* xa_bf  = (unsigned short*)ws;                 //  8,388,608 (x_bf, later attn_bf)
  unsigned short* Win_bf = (unsigned short*)(ws + 8388608);     //  6,291,456
  unsigned short* Wout_bf= (unsigned short*)(ws + 14680064);    //  2,097,152
  unsigned short* qkv_bf = (unsigned short*)(ws + 16777216);    // 25,165,824 (q,k cols only)
  unsigned short* vT     = (unsigned short*)(ws + 41943040);    //  8,388,608
  float* q_rel = (float*)(ws + 50331648);                       //      8,192
  float* e_arr = (float*)(ws + 50339840);                       //    262,144
  float* inv_a = (float*)(ws + 50601984);                       //    262,144
  float* w_row = (float*)(ws + 50864128);                       //    262,144
  unsigned short* Wc_bf  = (unsigned short*)(ws + 51126272);    //      8,192

  hipMemsetAsync(q_rel, 0, BHEADS * HD * sizeof(float), stream);

  // 0) one fused convert: x, W_in, W_out, Wc
  {
    const int na = M * D_EMB, nb = 3 * D_EMB * D_EMB, nc = D_EMB * D_EMB, nd = HD * HD;
    cvt4_bf16_kernel<<<dim3((na + nb + nc + nd) / 1024), 256, 0, stream>>>(
        x, na, W_in, nb, W_out, nc, Wc, nd, xa_bf, Win_bf, Wout_bf, Wc_bf);
  }
  // 1) qkv = x @ W_in^T + b_in -> bf16 q,k + transposed bf16 vT
  gemm_qkv<<<dim3(24, 32), 256, 0, stream>>>(
      xa_bf, Win_bf, b_in, qkv_bf, vT, M, 3 * D_EMB, D_EMB);
  // 2) q_temp -> q_rel sums (MFMA, 512 blocks)
  qtemp_mfma_kernel<<<dim3(16, BHEADS), 256, 0, stream>>>(
      qkv_bf, Wc_bf, bc, gamma, beta, q_rel);
  // 3) w_row gemv
  wrow_kernel<<<dim3(BHEADS, 8), 256, 0, stream>>>(qkv_bf, q_rel, w_row);
  // 4) softmax scan
  scan_kernel<<<dim3(BHEADS), 256, 0, stream>>>(w_row, e_arr, inv_a);
  // 5) weights.mean -> second output (independent of conv; fills GPU while small)
  wmean_kernel<<<dim3(BHEADS, L_SEQ / 128), 256, 0, stream>>>(
      e_arr, inv_a, out + (size_t)M * D_EMB);
  // 6) causal Toeplitz conv via MFMA, d-split (512 blocks) -> attn bf16
  conv_mfma_kernel<<<dim3(8, BHEADS, 2), 256, 0, stream>>>(vT, e_arr, inv_a, xa_bf);
  // 7) output = attn @ W_out^T + b_out (64x128 tiles, 512 blocks)
  gemm_out64<<<dim3(D_EMB / 128, M / 64), 256, 0, stream>>>(
      xa_bf, Wout_bf, b_out, out, M, D_EMB, D_EMB);
}